// Round 1
// baseline (1062.684 us; speedup 1.0000x reference)
//
#include <hip/hip_runtime.h>
#include <hip/hip_bf16.h>
#include <stdint.h>

// Problem constants
#define MTOK 16384   // B*S
#define HID  2048
#define NQKV 6144    // 3*HID

typedef __attribute__((ext_vector_type(8))) short bf16x8;
typedef __attribute__((ext_vector_type(4))) float f32x4;

__device__ __forceinline__ unsigned short f2bf(float f) {
  uint32_t u = __float_as_uint(f);
  u = (u + 0x7FFFu + ((u >> 16) & 1u)) >> 16;   // round-to-nearest-even
  return (unsigned short)u;
}
__device__ __forceinline__ float bf2f(unsigned short h) {
  return __uint_as_float(((uint32_t)h) << 16);
}
__device__ __forceinline__ void bf2x2(uint32_t u, float& lo, float& hi) {
  lo = __uint_as_float(u << 16);
  hi = __uint_as_float(u & 0xFFFF0000u);
}

__device__ __forceinline__ void gld_lds16(const void* g, void* l) {
  __builtin_amdgcn_global_load_lds(
      (const __attribute__((address_space(1))) uint32_t*)g,
      (__attribute__((address_space(3))) uint32_t*)l, 16, 0, 0);
}

// ---------------- fp32 -> bf16 elementwise convert (8 elems/thread/iter) ---
__global__ void convert_f32_bf16(const float* __restrict__ in,
                                 unsigned short* __restrict__ out, int n8) {
  int idx = blockIdx.x * blockDim.x + threadIdx.x;
  int stride = gridDim.x * blockDim.x;
  for (int i = idx; i < n8; i += stride) {
    const float4* p = (const float4*)(in + (size_t)i * 8);
    float4 a = p[0], b = p[1];
    union { bf16x8 v; unsigned short u[8]; } o;
    o.u[0] = f2bf(a.x); o.u[1] = f2bf(a.y); o.u[2] = f2bf(a.z); o.u[3] = f2bf(a.w);
    o.u[4] = f2bf(b.x); o.u[5] = f2bf(b.y); o.u[6] = f2bf(b.z); o.u[7] = f2bf(b.w);
    *(bf16x8*)(out + (size_t)i * 8) = o.v;
  }
}

// ---------------- W[K][N] f32  ->  Wt[N][K] bf16 (64x64 LDS tiles) ---------
__global__ void transpose_to_bf16(const float* __restrict__ W,
                                  unsigned short* __restrict__ Wt,
                                  int rows /*K*/, int cols /*N*/) {
  __shared__ float tile[64][65];
  int tk = blockIdx.x * 64, tn = blockIdx.y * 64;
  int t = threadIdx.x;
  int c = t & 63, rb = t >> 6;
#pragma unroll
  for (int i = 0; i < 16; i++) {
    int r = i * 4 + rb;
    tile[r][c] = W[(size_t)(tk + r) * cols + tn + c];
  }
  __syncthreads();
#pragma unroll
  for (int i = 0; i < 16; i++) {
    int r = i * 4 + rb;  // r = n index, c = k index
    Wt[(size_t)(tn + r) * rows + tk + c] = f2bf(tile[c][r]);
  }
}

// ---------------- bias concat [bq|bk|bv] -> [6144] f32 ---------------------
__global__ void concat_bias(const float* __restrict__ bq,
                            const float* __restrict__ bk,
                            const float* __restrict__ bv,
                            float* __restrict__ out) {
  int i = blockIdx.x * blockDim.x + threadIdx.x;
  if (i < 2048)       out[i] = bq[i];
  else if (i < 4096)  out[i] = bk[i - 2048];
  else if (i < 6144)  out[i] = bv[i - 4096];
}

// ---------------- bf16 GEMM: C[M][N] = A[M][K] * Bt[N][K]^T + bias ---------
// m97 structure: 128x128 tile, BK=32, 4 waves (2x2), global_load_lds staging.
template <bool F32OUT>
__global__ __launch_bounds__(256) void gemm_bf16_nt(
    const unsigned short* __restrict__ A,   // [M][K] bf16
    const unsigned short* __restrict__ Bt,  // [N][K] bf16 (pre-transposed)
    const float* __restrict__ bias,         // [N] f32
    unsigned short* __restrict__ Cb,        // bf16 out (if !F32OUT)
    float* __restrict__ Cf,                 // f32 out (if F32OUT)
    int M, int N, int K) {
  constexpr int BM = 128, BN = 128, BK = 32;
  __shared__ __align__(16) unsigned short smA[BM * BK];
  __shared__ __align__(16) unsigned short smB[BN * BK];

  const int tm = blockIdx.x, tn = blockIdx.y;
  const int tid = threadIdx.x;
  const int wave = tid >> 6, lane = tid & 63;
  const int wr = wave >> 1, wc = wave & 1;

  f32x4 acc[4][4];
#pragma unroll
  for (int m = 0; m < 4; m++)
#pragma unroll
    for (int n = 0; n < 4; n++) acc[m][n] = (f32x4){0.f, 0.f, 0.f, 0.f};

  const int lrow = lane >> 2;       // 0..15: row within 16-row staging group
  const int lk8 = (lane & 3) * 8;   // 0/8/16/24: k-element offset
  const unsigned short* Abase = A + (size_t)(tm * BM) * K + lk8;
  const unsigned short* Bbase = Bt + (size_t)(tn * BN) * K + lk8;

  const int fr = lane & 15;         // fragment row/col
  const int fk = (lane >> 4) * 8;   // fragment k offset

  for (int k0 = 0; k0 < K; k0 += BK) {
    // stage A[128][32] and B[128][32] into LDS (linear layout, lane-ordered)
    const unsigned short* ga = Abase + (size_t)(wave * 32 + lrow) * K + k0;
    const unsigned short* gb = Bbase + (size_t)(wave * 32 + lrow) * K + k0;
    gld_lds16(ga,                &smA[wave * 1024]);
    gld_lds16(ga + (size_t)16 * K, &smA[wave * 1024 + 512]);
    gld_lds16(gb,                &smB[wave * 1024]);
    gld_lds16(gb + (size_t)16 * K, &smB[wave * 1024 + 512]);
    __syncthreads();

    bf16x8 af[4], bf[4];
#pragma unroll
    for (int m = 0; m < 4; m++)
      af[m] = *(const bf16x8*)&smA[(wr * 64 + m * 16 + fr) * BK + fk];
#pragma unroll
    for (int n = 0; n < 4; n++)
      bf[n] = *(const bf16x8*)&smB[(wc * 64 + n * 16 + fr) * BK + fk];
#pragma unroll
    for (int m = 0; m < 4; m++)
#pragma unroll
      for (int n = 0; n < 4; n++)
        acc[m][n] = __builtin_amdgcn_mfma_f32_16x16x32_bf16(af[m], bf[n],
                                                            acc[m][n], 0, 0, 0);
    __syncthreads();
  }

  // epilogue: C/D layout col=lane&15, row=(lane>>4)*4+reg  [m89-verified]
  const int fq = lane >> 4;
#pragma unroll
  for (int m = 0; m < 4; m++) {
#pragma unroll
    for (int n = 0; n < 4; n++) {
      int col = tn * BN + wc * 64 + n * 16 + fr;
      float bb = bias ? bias[col] : 0.f;
#pragma unroll
      for (int r = 0; r < 4; r++) {
        int row = tm * BM + wr * 64 + m * 16 + fq * 4 + r;
        float v = acc[m][n][r] + bb;
        if constexpr (F32OUT) Cf[(size_t)row * N + col] = v;
        else                  Cb[(size_t)row * N + col] = f2bf(v);
      }
    }
  }
}

// ---------------- per-token 16x16 head-attention ---------------------------
// 1 wave per token; QKV rows staged in LDS (stride 136 keeps b128 aligned and
// rows ~2-way banked); softmax via 16-lane shfl_xor reduce; PV in VALU.
__global__ __launch_bounds__(256) void attn_kernel(
    const unsigned short* __restrict__ qkv,  // [MTOK][6144] bf16
    unsigned short* __restrict__ attn,       // [MTOK][2048] bf16
    const float* __restrict__ c_scale) {
  constexpr int QS = 136;  // padded row stride (elements)
  __shared__ __align__(16) unsigned short qkvs[4][3][16 * QS];
  __shared__ float ps[4][16 * 17];

  const int wave = threadIdx.x >> 6, lane = threadIdx.x & 63;
  const int tok = blockIdx.x * 4 + wave;
  const unsigned short* src = qkv + (size_t)tok * NQKV;

  // stage q,k,v [16][128] each
  const int rr = lane >> 4;          // row-in-group 0..3
  const int cc = (lane & 15) * 8;    // element offset in row
#pragma unroll
  for (int mtx = 0; mtx < 3; mtx++) {
#pragma unroll
    for (int i = 0; i < 4; i++) {
      int h = i * 4 + rr;
      bf16x8 v = *(const bf16x8*)(src + mtx * HID + h * 128 + cc);
      *(bf16x8*)&qkvs[wave][mtx][h * QS + cc] = v;
    }
  }
  // wave-private LDS slice: no __syncthreads needed (compiler orders via lgkmcnt)

  const float scale = c_scale[0] * 0.08838834764831845f;  // 1/sqrt(128)

  // scores + softmax: iter it covers rows h = it*4 + (lane>>4); g = lane&15
  const int g = lane & 15;
#pragma unroll
  for (int it = 0; it < 4; it++) {
    int h = it * 4 + (lane >> 4);
    float s = 0.f;
#pragma unroll
    for (int c8 = 0; c8 < 16; c8++) {
      uint4 qv = *(const uint4*)&qkvs[wave][0][h * QS + c8 * 8];
      uint4 kv = *(const uint4*)&qkvs[wave][1][g * QS + c8 * 8];
      float ql, qh, kl, kh;
      bf2x2(qv.x, ql, qh); bf2x2(kv.x, kl, kh); s += ql * kl + qh * kh;
      bf2x2(qv.y, ql, qh); bf2x2(kv.y, kl, kh); s += ql * kl + qh * kh;
      bf2x2(qv.z, ql, qh); bf2x2(kv.z, kl, kh); s += ql * kl + qh * kh;
      bf2x2(qv.w, ql, qh); bf2x2(kv.w, kl, kh); s += ql * kl + qh * kh;
    }
    s *= scale;
    float mx = s;
    mx = fmaxf(mx, __shfl_xor(mx, 1));
    mx = fmaxf(mx, __shfl_xor(mx, 2));
    mx = fmaxf(mx, __shfl_xor(mx, 4));
    mx = fmaxf(mx, __shfl_xor(mx, 8));
    float e = __expf(s - mx);
    float sum = e;
    sum += __shfl_xor(sum, 1);
    sum += __shfl_xor(sum, 2);
    sum += __shfl_xor(sum, 4);
    sum += __shfl_xor(sum, 8);
    ps[wave][h * 17 + g] = e / sum;
  }

  // PV: lane owns h = lane>>2, d = (lane&3)*32 .. +31
  const int h = lane >> 2;
  const int d0 = (lane & 3) * 32;
  float accv[32];
#pragma unroll
  for (int j = 0; j < 32; j++) accv[j] = 0.f;
#pragma unroll
  for (int gg = 0; gg < 16; gg++) {
    float p = ps[wave][h * 17 + gg];
#pragma unroll
    for (int c8 = 0; c8 < 4; c8++) {
      uint4 vv = *(const uint4*)&qkvs[wave][2][gg * QS + d0 + c8 * 8];
      float lo, hi;
      bf2x2(vv.x, lo, hi); accv[c8 * 8 + 0] += p * lo; accv[c8 * 8 + 1] += p * hi;
      bf2x2(vv.y, lo, hi); accv[c8 * 8 + 2] += p * lo; accv[c8 * 8 + 3] += p * hi;
      bf2x2(vv.z, lo, hi); accv[c8 * 8 + 4] += p * lo; accv[c8 * 8 + 5] += p * hi;
      bf2x2(vv.w, lo, hi); accv[c8 * 8 + 6] += p * lo; accv[c8 * 8 + 7] += p * hi;
    }
  }
  unsigned short* dst = attn + (size_t)tok * HID + h * 128 + d0;
#pragma unroll
  for (int c8 = 0; c8 < 4; c8++) {
    union { bf16x8 v; unsigned short u[8]; } o;
#pragma unroll
    for (int j = 0; j < 8; j++) o.u[j] = f2bf(accv[c8 * 8 + j]);
    *(bf16x8*)(dst + c8 * 8) = o.v;
  }
}

// ---------------------------------------------------------------------------
extern "C" void kernel_launch(void* const* d_in, const int* in_sizes, int n_in,
                              void* d_out, int out_size, void* d_ws,
                              size_t ws_size, hipStream_t stream) {
  const float* x  = (const float*)d_in[0];
  const float* Wq = (const float*)d_in[1];
  const float* bq = (const float*)d_in[2];
  const float* Wk = (const float*)d_in[3];
  const float* bk = (const float*)d_in[4];
  const float* Wv = (const float*)d_in[5];
  const float* bv = (const float*)d_in[6];
  const float* Wo = (const float*)d_in[7];
  const float* bo = (const float*)d_in[8];
  const float* c_scale = (const float*)d_in[9];
  float* out = (float*)d_out;

  char* ws = (char*)d_ws;
  unsigned short* xb    = (unsigned short*)ws; ws += (size_t)MTOK * HID * 2;
  unsigned short* Wqkvt = (unsigned short*)ws; ws += (size_t)NQKV * HID * 2;
  unsigned short* Wot   = (unsigned short*)ws; ws += (size_t)HID * HID * 2;
  float*          biasq = (float*)ws;          ws += (size_t)NQKV * 4;
  unsigned short* qkv   = (unsigned short*)ws; ws += (size_t)MTOK * NQKV * 2;
  unsigned short* attn  = (unsigned short*)ws; ws += (size_t)MTOK * HID * 2;

  convert_f32_bf16<<<4096, 256, 0, stream>>>(x, xb, MTOK * HID / 8);
  dim3 tg(32, 32);
  transpose_to_bf16<<<tg, 256, 0, stream>>>(Wq, Wqkvt, HID, HID);
  transpose_to_bf16<<<tg, 256, 0, stream>>>(Wk, Wqkvt + (size_t)HID * HID, HID, HID);
  transpose_to_bf16<<<tg, 256, 0, stream>>>(Wv, Wqkvt + (size_t)2 * HID * HID, HID, HID);
  transpose_to_bf16<<<tg, 256, 0, stream>>>(Wo, Wot, HID, HID);
  concat_bias<<<24, 256, 0, stream>>>(bq, bk, bv, biasq);

  gemm_bf16_nt<false><<<dim3(MTOK / 128, NQKV / 128), 256, 0, stream>>>(
      xb, Wqkvt, biasq, qkv, nullptr, MTOK, NQKV, HID);
  attn_kernel<<<MTOK / 4, 256, 0, stream>>>(qkv, attn, c_scale);
  gemm_bf16_nt<true><<<dim3(MTOK / 128, HID / 128), 256, 0, stream>>>(
      attn, Wot, bo, nullptr, out, MTOK, HID, HID);
}

// Round 2
// 847.140 us; speedup vs baseline: 1.2544x; 1.2544x over previous
//
#include <hip/hip_runtime.h>
#include <hip/hip_bf16.h>
#include <stdint.h>

// Problem constants
#define MTOK 16384   // B*S
#define HID  2048
#define NQKV 6144    // 3*HID
#define GK   2048    // K of both GEMMs
#define NKT  (GK / 64)    // 32 K-tiles
#define NREG (NKT * 4)    // 128 staging regions (A_k0,B_k0,A_k1,B_k1 per tile)

typedef __attribute__((ext_vector_type(8))) short bf16x8;
typedef __attribute__((ext_vector_type(4))) float f32x4;

__device__ __forceinline__ unsigned short f2bf(float f) {
  uint32_t u = __float_as_uint(f);
  u = (u + 0x7FFFu + ((u >> 16) & 1u)) >> 16;   // round-to-nearest-even
  return (unsigned short)u;
}
__device__ __forceinline__ void bf2x2(uint32_t u, float& lo, float& hi) {
  lo = __uint_as_float(u << 16);
  hi = __uint_as_float(u & 0xFFFF0000u);
}

__device__ __forceinline__ void gld_lds16(const void* g, void* l) {
  __builtin_amdgcn_global_load_lds(
      (const __attribute__((address_space(1))) uint32_t*)g,
      (__attribute__((address_space(3))) uint32_t*)l, 16, 0, 0);
}

// ---------------- fp32 -> bf16 elementwise convert (8 elems/thread/iter) ---
__global__ void convert_f32_bf16(const float* __restrict__ in,
                                 unsigned short* __restrict__ out, int n8) {
  int idx = blockIdx.x * blockDim.x + threadIdx.x;
  int stride = gridDim.x * blockDim.x;
  for (int i = idx; i < n8; i += stride) {
    const float4* p = (const float4*)(in + (size_t)i * 8);
    float4 a = p[0], b = p[1];
    union { bf16x8 v; unsigned short u[8]; } o;
    o.u[0] = f2bf(a.x); o.u[1] = f2bf(a.y); o.u[2] = f2bf(a.z); o.u[3] = f2bf(a.w);
    o.u[4] = f2bf(b.x); o.u[5] = f2bf(b.y); o.u[6] = f2bf(b.z); o.u[7] = f2bf(b.w);
    *(bf16x8*)(out + (size_t)i * 8) = o.v;
  }
}

// ---------------- W[K][N] f32  ->  Wt[N][K] bf16 (64x64 LDS tiles) ---------
__global__ void transpose_to_bf16(const float* __restrict__ W,
                                  unsigned short* __restrict__ Wt,
                                  int rows /*K*/, int cols /*N*/) {
  __shared__ float tile[64][65];
  int tk = blockIdx.x * 64, tn = blockIdx.y * 64;
  int t = threadIdx.x;
  int c = t & 63, rb = t >> 6;
#pragma unroll
  for (int i = 0; i < 16; i++) {
    int r = i * 4 + rb;
    tile[r][c] = W[(size_t)(tk + r) * cols + tn + c];
  }
  __syncthreads();
#pragma unroll
  for (int i = 0; i < 16; i++) {
    int r = i * 4 + rb;  // r = n index, c = k index
    Wt[(size_t)(tn + r) * rows + tk + c] = f2bf(tile[c][r]);
  }
}

// ---------------- bias concat [bq|bk|bv] -> [6144] f32 ---------------------
__global__ void concat_bias(const float* __restrict__ bq,
                            const float* __restrict__ bk,
                            const float* __restrict__ bv,
                            float* __restrict__ out) {
  int i = blockIdx.x * blockDim.x + threadIdx.x;
  if (i < 2048)       out[i] = bq[i];
  else if (i < 4096)  out[i] = bk[i - 2048];
  else if (i < 6144)  out[i] = bv[i - 4096];
}

// ===========================================================================
// 256x256 8-phase bf16 GEMM (T1+T2+T3+T4+T5), C[M][N] = A[M][K]*Bt[N][K]^T + b
//
// LDS map (131072 B dynamic): byte = buf<<16 | stream<<15 | kstep<<14 |
//   row*64 | colbyte, region [256][32] bf16. Swizzle (involution):
//   byte ^= ((row>>1)&3)<<4  -- applied on ds_read addr AND inverted on the
//   global source of global_load_lds (linear LDS dest), rule #21.
// Schedule: phase p of tile u stages region S_{4u+p+6}; vmcnt(4) at p1/p3.
//   WAR: every stage issue is >=1 barrier after last read of its region.
//   RAW: per-wave vmcnt(4) + the phase barriers land regions >=1 phase early.
// ===========================================================================
template <bool F32OUT>
__global__ __launch_bounds__(512, 2) void gemm256(
    const unsigned short* __restrict__ A,   // [M][GK] bf16
    const unsigned short* __restrict__ Bt,  // [N][GK] bf16
    const float* __restrict__ bias,         // [N]
    unsigned short* __restrict__ Cb, float* __restrict__ Cf,
    int M, int N) {
  extern __shared__ __align__(16) char lds[];

  // XCD-bijective block swizzle (grid % 8 == 0 for both shapes)
  const int nwg = gridDim.x;
  const int bid = blockIdx.x;
  const int wg = (bid & 7) * (nwg >> 3) + (bid >> 3);
  const int ntm = M >> 8;
  const int tm = wg % ntm, tn = wg / ntm;

  const int tid = threadIdx.x;
  const int wave = tid >> 6, lane = tid & 63;
  const int wr = wave >> 2, wc = wave & 3;   // 2M x 4N waves, 128x64 out each

  // ---- staging addressing (per-thread, bytes) ----
  // dest (linear) region offset q = r*8192 + tid*16 -> row=q>>6, then source
  // col-byte = (q&63) ^ swz(row); swz(row)=((row>>1)&3)<<4 is r-independent.
  const int colb = ((tid & 3) << 4) ^ (((tid >> 3) & 3) << 4);
  const size_t g0 = (size_t)(tid >> 2) * (GK * 2) + colb;
  const size_t g1 = g0 + (size_t)128 * (GK * 2);
  const char* Ab = (const char*)A + (size_t)tm * 256 * (GK * 2);
  const char* Bb = (const char*)Bt + (size_t)tn * 256 * (GK * 2);

#define STAGE(J)                                                          \
  do {                                                                    \
    if ((J) < NREG) {                                                     \
      const int _t = (J) >> 2;                                            \
      const char* _s = (((J)&1) ? Bb : Ab) +                              \
                       (size_t)(_t)*128 + ((((J) >> 1) & 1) * 64);        \
      char* _d = lds + ((_t & 1) << 16) + (((J)&1) << 15) +               \
                 ((((J) >> 1) & 1) << 14) + (wave << 10);                 \
      gld_lds16(_s + g0, _d);                                             \
      gld_lds16(_s + g1, _d + 8192);                                      \
    }                                                                     \
  } while (0)

  // ---- fragment read addressing ----
  const int fr = lane & 15;
  const int fkb = (lane >> 4) << 4;                      // k-offset bytes
  const int lofs = fr * 64 + (fkb ^ (((fr >> 1) & 3) << 4));  // swizzled
  const char* aL = lds + wr * 8192 + lofs;  // + buf + ks*16384 + mh*4096 + m*1024
  const char* bL = lds + 32768 + wc * 4096 + lofs;  // + buf + ks*16384 + n*1024

  f32x4 acc[8][4];
#pragma unroll
  for (int m = 0; m < 8; m++)
#pragma unroll
    for (int n = 0; n < 4; n++) acc[m][n] = (f32x4){0.f, 0.f, 0.f, 0.f};
  bf16x8 aF[4], bF[4];

  // ---- prologue: stage S_0..S_5 (tile0 + A_k0,B_k0 of tile1) ----
  STAGE(0); STAGE(1); STAGE(2); STAGE(3); STAGE(4); STAGE(5);
  asm volatile("s_waitcnt vmcnt(4)" ::: "memory");  // tile0 fully landed
  __builtin_amdgcn_s_barrier();

#define PHASE(PH, MH, KS, RDB)                                               \
  do {                                                                       \
    if (((PH)&1) == 0) asm volatile("s_waitcnt vmcnt(4)" ::: "memory");      \
    const char* _a = aL + bufo + (KS)*16384 + (MH)*4096;                     \
    _Pragma("unroll") for (int m = 0; m < 4; m++)                            \
        aF[m] = *(const bf16x8*)(_a + m * 1024);                             \
    if (RDB) {                                                               \
      const char* _b = bL + bufo + (KS)*16384;                               \
      _Pragma("unroll") for (int n = 0; n < 4; n++)                          \
          bF[n] = *(const bf16x8*)(_b + n * 1024);                           \
    }                                                                        \
    STAGE(u * 4 + (PH) + 6);                                                 \
    __builtin_amdgcn_s_barrier();                                            \
    asm volatile("s_waitcnt lgkmcnt(0)" ::: "memory");                       \
    __builtin_amdgcn_s_setprio(1);                                           \
    _Pragma("unroll") for (int m = 0; m < 4; m++)                            \
        _Pragma("unroll") for (int n = 0; n < 4; n++)                        \
            acc[(MH)*4 + m][n] = __builtin_amdgcn_mfma_f32_16x16x32_bf16(    \
                aF[m], bF[n], acc[(MH)*4 + m][n], 0, 0, 0);                  \
    __builtin_amdgcn_s_setprio(0);                                           \
    __builtin_amdgcn_s_barrier();                                            \
  } while (0)

  for (int u = 0; u < NKT; ++u) {
    const int bufo = (u & 1) << 16;
    PHASE(0, 0, 0, 1);
    PHASE(1, 1, 0, 0);
    PHASE(2, 0, 1, 1);
    PHASE(3, 1, 1, 0);
  }
#undef PHASE
#undef STAGE

  // ---- epilogue: C/D layout col=lane&15, row=(lane>>4)*4+reg ----
  const int fq = lane >> 4;
#pragma unroll
  for (int mp = 0; mp < 8; mp++) {
#pragma unroll
    for (int n = 0; n < 4; n++) {
      const int col = tn * 256 + wc * 64 + n * 16 + fr;
      const float bb = bias[col];
#pragma unroll
      for (int r = 0; r < 4; r++) {
        const int row = tm * 256 + wr * 128 + mp * 16 + fq * 4 + r;
        const float v = acc[mp][n][r] + bb;
        if constexpr (F32OUT) Cf[(size_t)row * N + col] = v;
        else                  Cb[(size_t)row * N + col] = f2bf(v);
      }
    }
  }
}

// ---------------- per-token 16x16 head-attention ---------------------------
__global__ __launch_bounds__(256) void attn_kernel(
    const unsigned short* __restrict__ qkv,  // [MTOK][6144] bf16
    unsigned short* __restrict__ attn,       // [MTOK][2048] bf16
    const float* __restrict__ c_scale) {
  constexpr int QS = 136;  // padded row stride (elements)
  __shared__ __align__(16) unsigned short qkvs[4][3][16 * QS];
  __shared__ float ps[4][16 * 17];

  const int wave = threadIdx.x >> 6, lane = threadIdx.x & 63;
  const int tok = blockIdx.x * 4 + wave;
  const unsigned short* src = qkv + (size_t)tok * NQKV;

  const int rr = lane >> 4;
  const int cc = (lane & 15) * 8;
#pragma unroll
  for (int mtx = 0; mtx < 3; mtx++) {
#pragma unroll
    for (int i = 0; i < 4; i++) {
      int h = i * 4 + rr;
      bf16x8 v = *(const bf16x8*)(src + mtx * HID + h * 128 + cc);
      *(bf16x8*)&qkvs[wave][mtx][h * QS + cc] = v;
    }
  }

  const float scale = c_scale[0] * 0.08838834764831845f;  // 1/sqrt(128)

  const int g = lane & 15;
#pragma unroll
  for (int it = 0; it < 4; it++) {
    int h = it * 4 + (lane >> 4);
    float s = 0.f;
#pragma unroll
    for (int c8 = 0; c8 < 16; c8++) {
      uint4 qv = *(const uint4*)&qkvs[wave][0][h * QS + c8 * 8];
      uint4 kv = *(const uint4*)&qkvs[wave][1][g * QS + c8 * 8];
      float ql, qh, kl, kh;
      bf2x2(qv.x, ql, qh); bf2x2(kv.x, kl, kh); s += ql * kl + qh * kh;
      bf2x2(qv.y, ql, qh); bf2x2(kv.y, kl, kh); s += ql * kl + qh * kh;
      bf2x2(qv.z, ql, qh); bf2x2(kv.z, kl, kh); s += ql * kl + qh * kh;
      bf2x2(qv.w, ql, qh); bf2x2(kv.w, kl, kh); s += ql * kl + qh * kh;
    }
    s *= scale;
    float mx = s;
    mx = fmaxf(mx, __shfl_xor(mx, 1));
    mx = fmaxf(mx, __shfl_xor(mx, 2));
    mx = fmaxf(mx, __shfl_xor(mx, 4));
    mx = fmaxf(mx, __shfl_xor(mx, 8));
    float e = __expf(s - mx);
    float sum = e;
    sum += __shfl_xor(sum, 1);
    sum += __shfl_xor(sum, 2);
    sum += __shfl_xor(sum, 4);
    sum += __shfl_xor(sum, 8);
    ps[wave][h * 17 + g] = e / sum;
  }

  const int h = lane >> 2;
  const int d0 = (lane & 3) * 32;
  float accv[32];
#pragma unroll
  for (int j = 0; j < 32; j++) accv[j] = 0.f;
#pragma unroll
  for (int gg = 0; gg < 16; gg++) {
    float p = ps[wave][h * 17 + gg];
#pragma unroll
    for (int c8 = 0; c8 < 4; c8++) {
      uint4 vv = *(const uint4*)&qkvs[wave][2][gg * QS + d0 + c8 * 8];
      float lo, hi;
      bf2x2(vv.x, lo, hi); accv[c8 * 8 + 0] += p * lo; accv[c8 * 8 + 1] += p * hi;
      bf2x2(vv.y, lo, hi); accv[c8 * 8 + 2] += p * lo; accv[c8 * 8 + 3] += p * hi;
      bf2x2(vv.z, lo, hi); accv[c8 * 8 + 4] += p * lo; accv[c8 * 8 + 5] += p * hi;
      bf2x2(vv.w, lo, hi); accv[c8 * 8 + 6] += p * lo; accv[c8 * 8 + 7] += p * hi;
    }
  }
  unsigned short* dst = attn + (size_t)tok * HID + h * 128 + d0;
#pragma unroll
  for (int c8 = 0; c8 < 4; c8++) {
    union { bf16x8 v; unsigned short u[8]; } o;
#pragma unroll
    for (int j = 0; j < 8; j++) o.u[j] = f2bf(accv[c8 * 8 + j]);
    *(bf16x8*)(dst + c8 * 8) = o.v;
  }
}

// ---------------------------------------------------------------------------
extern "C" void kernel_launch(void* const* d_in, const int* in_sizes, int n_in,
                              void* d_out, int out_size, void* d_ws,
                              size_t ws_size, hipStream_t stream) {
  const float* x  = (const float*)d_in[0];
  const float* Wq = (const float*)d_in[1];
  const float* bq = (const float*)d_in[2];
  const float* Wk = (const float*)d_in[3];
  const float* bk = (const float*)d_in[4];
  const float* Wv = (const float*)d_in[5];
  const float* bv = (const float*)d_in[6];
  const float* Wo = (const float*)d_in[7];
  const float* bo = (const float*)d_in[8];
  const float* c_scale = (const float*)d_in[9];
  float* out = (float*)d_out;

  char* ws = (char*)d_ws;
  unsigned short* xb    = (unsigned short*)ws; ws += (size_t)MTOK * HID * 2;
  unsigned short* Wqkvt = (unsigned short*)ws; ws += (size_t)NQKV * HID * 2;
  unsigned short* Wot   = (unsigned short*)ws; ws += (size_t)HID * HID * 2;
  float*          biasq = (float*)ws;          ws += (size_t)NQKV * 4;
  unsigned short* qkv   = (unsigned short*)ws; ws += (size_t)MTOK * NQKV * 2;
  unsigned short* attn  = (unsigned short*)ws; ws += (size_t)MTOK * HID * 2;

  (void)hipFuncSetAttribute((const void*)&gemm256<false>,
                            hipFuncAttributeMaxDynamicSharedMemorySize, 131072);
  (void)hipFuncSetAttribute((const void*)&gemm256<true>,
                            hipFuncAttributeMaxDynamicSharedMemorySize, 131072);

  convert_f32_bf16<<<4096, 256, 0, stream>>>(x, xb, MTOK * HID / 8);
  dim3 tg(32, 32);
  transpose_to_bf16<<<tg, 256, 0, stream>>>(Wq, Wqkvt, HID, HID);
  transpose_to_bf16<<<tg, 256, 0, stream>>>(Wk, Wqkvt + (size_t)HID * HID, HID, HID);
  transpose_to_bf16<<<tg, 256, 0, stream>>>(Wv, Wqkvt + (size_t)2 * HID * HID, HID, HID);
  transpose_to_bf16<<<tg, 256, 0, stream>>>(Wo, Wot, HID, HID);
  concat_bias<<<24, 256, 0, stream>>>(bq, bk, bv, biasq);

  // QKV projection: [16384][2048] x [6144][2048]^T -> bf16 [16384][6144]
  gemm256<false><<<(MTOK / 256) * (NQKV / 256), 512, 131072, stream>>>(
      xb, Wqkvt, biasq, qkv, nullptr, MTOK, NQKV);
  attn_kernel<<<MTOK / 4, 256, 0, stream>>>(qkv, attn, c_scale);
  // O projection: [16384][2048] x [2048][2048]^T -> f32 out
  gemm256<true><<<(MTOK / 256) * (HID / 256), 512, 131072, stream>>>(
      attn, Wot, bo, nullptr, out, MTOK, HID);
}

// Round 3
// 845.731 us; speedup vs baseline: 1.2565x; 1.0017x over previous
//
#include <hip/hip_runtime.h>
#include <hip/hip_bf16.h>
#include <stdint.h>

// Problem constants
#define MTOK 16384   // B*S
#define HID  2048
#define NQKV 6144    // 3*HID
#define GK   2048    // K of both GEMMs
#define NKT  (GK / 64)    // 32 K-tiles
#define NREG (NKT * 4)    // 128 staging regions (A_k0,B_k0,A_k1,B_k1 per tile)
#define SLOT 16384        // bytes per LDS region slot
#define RING (9 * SLOT)   // 147456 B: 9-slot ring

typedef __attribute__((ext_vector_type(8))) short bf16x8;
typedef __attribute__((ext_vector_type(4))) float f32x4;

__device__ __forceinline__ unsigned short f2bf(float f) {
  uint32_t u = __float_as_uint(f);
  u = (u + 0x7FFFu + ((u >> 16) & 1u)) >> 16;   // round-to-nearest-even
  return (unsigned short)u;
}
__device__ __forceinline__ void bf2x2(uint32_t u, float& lo, float& hi) {
  lo = __uint_as_float(u << 16);
  hi = __uint_as_float(u & 0xFFFF0000u);
}

__device__ __forceinline__ void gld_lds16(const void* g, void* l) {
  __builtin_amdgcn_global_load_lds(
      (const __attribute__((address_space(1))) uint32_t*)g,
      (__attribute__((address_space(3))) uint32_t*)l, 16, 0, 0);
}

// ---------------- fp32 -> bf16 elementwise convert (8 elems/thread/iter) ---
__global__ void convert_f32_bf16(const float* __restrict__ in,
                                 unsigned short* __restrict__ out, int n8) {
  int idx = blockIdx.x * blockDim.x + threadIdx.x;
  int stride = gridDim.x * blockDim.x;
  for (int i = idx; i < n8; i += stride) {
    const float4* p = (const float4*)(in + (size_t)i * 8);
    float4 a = p[0], b = p[1];
    union { bf16x8 v; unsigned short u[8]; } o;
    o.u[0] = f2bf(a.x); o.u[1] = f2bf(a.y); o.u[2] = f2bf(a.z); o.u[3] = f2bf(a.w);
    o.u[4] = f2bf(b.x); o.u[5] = f2bf(b.y); o.u[6] = f2bf(b.z); o.u[7] = f2bf(b.w);
    *(bf16x8*)(out + (size_t)i * 8) = o.v;
  }
}

// ------- 4x W[K][N] f32 -> Wt[N][K] bf16 (64x64 LDS tiles), z picks W ------
__global__ void transpose4_to_bf16(const float* __restrict__ Wq,
                                   const float* __restrict__ Wk,
                                   const float* __restrict__ Wv,
                                   const float* __restrict__ Wo,
                                   unsigned short* __restrict__ Wqkvt,
                                   unsigned short* __restrict__ Wot) {
  __shared__ float tile[64][65];
  const float* W;
  unsigned short* Wt;
  const int z = blockIdx.z;
  if (z == 0)      { W = Wq; Wt = Wqkvt; }
  else if (z == 1) { W = Wk; Wt = Wqkvt + (size_t)HID * HID; }
  else if (z == 2) { W = Wv; Wt = Wqkvt + (size_t)2 * HID * HID; }
  else             { W = Wo; Wt = Wot; }
  int tk = blockIdx.x * 64, tn = blockIdx.y * 64;
  int t = threadIdx.x;
  int c = t & 63, rb = t >> 6;
#pragma unroll
  for (int i = 0; i < 16; i++) {
    int r = i * 4 + rb;
    tile[r][c] = W[(size_t)(tk + r) * HID + tn + c];
  }
  __syncthreads();
#pragma unroll
  for (int i = 0; i < 16; i++) {
    int r = i * 4 + rb;  // r = n index, c = k index
    Wt[(size_t)(tn + r) * HID + tk + c] = f2bf(tile[c][r]);
  }
}

// ---------------- bias concat [bq|bk|bv] -> [6144] f32 ---------------------
__global__ void concat_bias(const float* __restrict__ bq,
                            const float* __restrict__ bk,
                            const float* __restrict__ bv,
                            float* __restrict__ out) {
  int i = blockIdx.x * blockDim.x + threadIdx.x;
  if (i < 2048)       out[i] = bq[i];
  else if (i < 4096)  out[i] = bk[i - 2048];
  else if (i < 6144)  out[i] = bv[i - 4096];
}

// ===========================================================================
// 256x256 8-phase bf16 GEMM (T1+T2+T3+T4+T5), C[M][N] = A[M][K]*Bt[N][K]^T + b
//
// LDS: 9-slot ring of 16 KiB regions (147456 B). Region = [256 rows][32 cols]
// bf16; region S_J (J = 4u + {0:A_k0,1:B_k0,2:A_k1,3:B_k1}) lives in slot
// (J mod 9). Swizzle involution byte ^= ((row>>1)&3)<<4 on ds_read addr,
// inverse pre-applied to the global source of global_load_lds (rule #21).
//
// Schedule (ledger-verified):
//  - phase p of tile u stages S_{4u+p+7} -> overwrites S_{4u+p-2}, whose last
//    read was phase p-2 (>=1 barrier separation for every p). WAR-safe.
//  - single vmcnt(6) at END of phase 3 (before the closing barrier): issued
//    through S_{4u+10}, so S_{4u+7} and older landed => tile u+1's regions
//    ready, 3 regions (6 loads) stay in flight. Barrier separates the drain
//    from all waves' next reads => cross-wave RAW-safe.
//  - prologue stages S_0..S_6, vmcnt(6), barrier.
// ===========================================================================
template <bool F32OUT>
__global__ __launch_bounds__(512, 2) void gemm256(
    const unsigned short* __restrict__ A,   // [M][GK] bf16
    const unsigned short* __restrict__ Bt,  // [N][GK] bf16
    const float* __restrict__ bias,         // [N]
    unsigned short* __restrict__ Cb, float* __restrict__ Cf,
    int M, int N) {
  extern __shared__ __align__(16) char lds[];

  // XCD-bijective block swizzle (grid % 8 == 0 for both shapes)
  const int nwg = gridDim.x;
  const int bid = blockIdx.x;
  const int wg = (bid & 7) * (nwg >> 3) + (bid >> 3);
  const int ntm = M >> 8;
  const int tm = wg % ntm, tn = wg / ntm;

  const int tid = threadIdx.x;
  const int wave = tid >> 6, lane = tid & 63;
  const int wr = wave >> 2, wc = wave & 3;   // 2M x 4N waves, 128x64 out each

  // ---- staging addressing (per-thread, bytes) ----
  const int colb = ((tid & 3) << 4) ^ (((tid >> 3) & 3) << 4);
  const size_t g0 = (size_t)(tid >> 2) * (GK * 2) + colb;
  const size_t g1 = g0 + (size_t)128 * (GK * 2);
  const char* Ab = (const char*)A + (size_t)tm * 256 * (GK * 2);
  const char* Bb = (const char*)Bt + (size_t)tn * 256 * (GK * 2);

#define STAGE(J, DST)                                                     \
  do {                                                                    \
    if ((J) < NREG) {                                                     \
      const int _t = (J) >> 2;                                            \
      const char* _s = (((J)&1) ? Bb : Ab) + (size_t)(_t)*128 +           \
                       ((((J) >> 1) & 1) * 64);                           \
      char* _d = lds + (DST) + (wave << 10);                              \
      gld_lds16(_s + g0, _d);                                             \
      gld_lds16(_s + g1, _d + 8192);                                      \
    }                                                                     \
  } while (0)

  // ---- fragment read addressing ----
  const int fr = lane & 15;
  const int fkb = (lane >> 4) << 4;                           // k-offset bytes
  const int lofs = fr * 64 + (fkb ^ (((fr >> 1) & 3) << 4));  // swizzled

  f32x4 acc[8][4];
#pragma unroll
  for (int m = 0; m < 8; m++)
#pragma unroll
    for (int n = 0; n < 4; n++) acc[m][n] = (f32x4){0.f, 0.f, 0.f, 0.f};
  bf16x8 aF[4], bF[4];

  // ---- ring cursors (uniform; compile-time-constant indexing only) ----
  int rs[4] = {0, SLOT, 2 * SLOT, 3 * SLOT};           // slots of S_{4u+0..3}
  int wsl[4] = {7 * SLOT, 8 * SLOT, 0, SLOT};          // slots of S_{4u+7..10}

  // ---- prologue: stage S_0..S_6 into slots 0..6 ----
  STAGE(0, 0); STAGE(1, SLOT); STAGE(2, 2 * SLOT); STAGE(3, 3 * SLOT);
  STAGE(4, 4 * SLOT); STAGE(5, 5 * SLOT); STAGE(6, 6 * SLOT);
  asm volatile("s_waitcnt vmcnt(6)" ::: "memory");  // S_0..S_3 landed
  __builtin_amdgcn_s_barrier();

#define PHASE(PH, MH, KS, RDB)                                               \
  do {                                                                       \
    const char* _a = lds + rs[(KS)*2] + wr * 8192 + (MH)*4096 + lofs;        \
    _Pragma("unroll") for (int m = 0; m < 4; m++)                            \
        aF[m] = *(const bf16x8*)(_a + m * 1024);                             \
    if (RDB) {                                                               \
      const char* _b = lds + rs[(KS)*2 + 1] + wc * 4096 + lofs;              \
      _Pragma("unroll") for (int n = 0; n < 4; n++)                          \
          bF[n] = *(const bf16x8*)(_b + n * 1024);                           \
    }                                                                        \
    STAGE(u * 4 + (PH) + 7, wsl[PH]);                                        \
    __builtin_amdgcn_s_barrier();                                            \
    asm volatile("s_waitcnt lgkmcnt(0)" ::: "memory");                       \
    __builtin_amdgcn_s_setprio(1);                                           \
    _Pragma("unroll") for (int m = 0; m < 4; m++)                            \
        _Pragma("unroll") for (int n = 0; n < 4; n++)                        \
            acc[(MH)*4 + m][n] = __builtin_amdgcn_mfma_f32_16x16x32_bf16(    \
                aF[m], bF[n], acc[(MH)*4 + m][n], 0, 0, 0);                  \
    __builtin_amdgcn_s_setprio(0);                                           \
    if ((PH) == 3) asm volatile("s_waitcnt vmcnt(6)" ::: "memory");          \
    __builtin_amdgcn_s_barrier();                                            \
  } while (0)

  for (int u = 0; u < NKT; ++u) {
    PHASE(0, 0, 0, 1);
    PHASE(1, 1, 0, 0);
    PHASE(2, 0, 1, 1);
    PHASE(3, 1, 1, 0);
#pragma unroll
    for (int i = 0; i < 4; i++) {
      rs[i] += 4 * SLOT;  if (rs[i] >= RING)  rs[i] -= RING;
      wsl[i] += 4 * SLOT; if (wsl[i] >= RING) wsl[i] -= RING;
    }
  }
#undef PHASE
#undef STAGE

  // ---- epilogue: C/D layout col=lane&15, row=(lane>>4)*4+reg ----
  const int fq = lane >> 4;
#pragma unroll
  for (int mp = 0; mp < 8; mp++) {
#pragma unroll
    for (int n = 0; n < 4; n++) {
      const int col = tn * 256 + wc * 64 + n * 16 + fr;
      const float bb = bias[col];
#pragma unroll
      for (int r = 0; r < 4; r++) {
        const int row = tm * 256 + wr * 128 + mp * 16 + fq * 4 + r;
        const float v = acc[mp][n][r] + bb;
        if constexpr (F32OUT) Cf[(size_t)row * N + col] = v;
        else                  Cb[(size_t)row * N + col] = f2bf(v);
      }
    }
  }
}

// ---------------- per-token 16x16 head-attention ---------------------------
__global__ __launch_bounds__(256) void attn_kernel(
    const unsigned short* __restrict__ qkv,  // [MTOK][6144] bf16
    unsigned short* __restrict__ attn,       // [MTOK][2048] bf16
    const float* __restrict__ c_scale) {
  constexpr int QS = 136;  // padded row stride (elements)
  __shared__ __align__(16) unsigned short qkvs[4][3][16 * QS];
  __shared__ float ps[4][16 * 17];

  const int wave = threadIdx.x >> 6, lane = threadIdx.x & 63;
  const int tok = blockIdx.x * 4 + wave;
  const unsigned short* src = qkv + (size_t)tok * NQKV;

  const int rr = lane >> 4;
  const int cc = (lane & 15) * 8;
#pragma unroll
  for (int mtx = 0; mtx < 3; mtx++) {
#pragma unroll
    for (int i = 0; i < 4; i++) {
      int h = i * 4 + rr;
      bf16x8 v = *(const bf16x8*)(src + mtx * HID + h * 128 + cc);
      *(bf16x8*)&qkvs[wave][mtx][h * QS + cc] = v;
    }
  }

  const float scale = c_scale[0] * 0.08838834764831845f;  // 1/sqrt(128)

  const int g = lane & 15;
#pragma unroll
  for (int it = 0; it < 4; it++) {
    int h = it * 4 + (lane >> 4);
    float s = 0.f;
#pragma unroll
    for (int c8 = 0; c8 < 16; c8++) {
      uint4 qv = *(const uint4*)&qkvs[wave][0][h * QS + c8 * 8];
      uint4 kv = *(const uint4*)&qkvs[wave][1][g * QS + c8 * 8];
      float ql, qh, kl, kh;
      bf2x2(qv.x, ql, qh); bf2x2(kv.x, kl, kh); s += ql * kl + qh * kh;
      bf2x2(qv.y, ql, qh); bf2x2(kv.y, kl, kh); s += ql * kl + qh * kh;
      bf2x2(qv.z, ql, qh); bf2x2(kv.z, kl, kh); s += ql * kl + qh * kh;
      bf2x2(qv.w, ql, qh); bf2x2(kv.w, kl, kh); s += ql * kl + qh * kh;
    }
    s *= scale;
    float mx = s;
    mx = fmaxf(mx, __shfl_xor(mx, 1));
    mx = fmaxf(mx, __shfl_xor(mx, 2));
    mx = fmaxf(mx, __shfl_xor(mx, 4));
    mx = fmaxf(mx, __shfl_xor(mx, 8));
    float e = __expf(s - mx);
    float sum = e;
    sum += __shfl_xor(sum, 1);
    sum += __shfl_xor(sum, 2);
    sum += __shfl_xor(sum, 4);
    sum += __shfl_xor(sum, 8);
    ps[wave][h * 17 + g] = e / sum;
  }

  const int h = lane >> 2;
  const int d0 = (lane & 3) * 32;
  float accv[32];
#pragma unroll
  for (int j = 0; j < 32; j++) accv[j] = 0.f;
#pragma unroll
  for (int gg = 0; gg < 16; gg++) {
    float p = ps[wave][h * 17 + gg];
#pragma unroll
    for (int c8 = 0; c8 < 4; c8++) {
      uint4 vv = *(const uint4*)&qkvs[wave][2][gg * QS + d0 + c8 * 8];
      float lo, hi;
      bf2x2(vv.x, lo, hi); accv[c8 * 8 + 0] += p * lo; accv[c8 * 8 + 1] += p * hi;
      bf2x2(vv.y, lo, hi); accv[c8 * 8 + 2] += p * lo; accv[c8 * 8 + 3] += p * hi;
      bf2x2(vv.z, lo, hi); accv[c8 * 8 + 4] += p * lo; accv[c8 * 8 + 5] += p * hi;
      bf2x2(vv.w, lo, hi); accv[c8 * 8 + 6] += p * lo; accv[c8 * 8 + 7] += p * hi;
    }
  }
  unsigned short* dst = attn + (size_t)tok * HID + h * 128 + d0;
#pragma unroll
  for (int c8 = 0; c8 < 4; c8++) {
    union { bf16x8 v; unsigned short u[8]; } o;
#pragma unroll
    for (int j = 0; j < 8; j++) o.u[j] = f2bf(accv[c8 * 8 + j]);
    *(bf16x8*)(dst + c8 * 8) = o.v;
  }
}

// ---------------------------------------------------------------------------
extern "C" void kernel_launch(void* const* d_in, const int* in_sizes, int n_in,
                              void* d_out, int out_size, void* d_ws,
                              size_t ws_size, hipStream_t stream) {
  const float* x  = (const float*)d_in[0];
  const float* Wq = (const float*)d_in[1];
  const float* bq = (const float*)d_in[2];
  const float* Wk = (const float*)d_in[3];
  const float* bk = (const float*)d_in[4];
  const float* Wv = (const float*)d_in[5];
  const float* bv = (const float*)d_in[6];
  const float* Wo = (const float*)d_in[7];
  const float* bo = (const float*)d_in[8];
  const float* c_scale = (const float*)d_in[9];
  float* out = (float*)d_out;

  char* ws = (char*)d_ws;
  unsigned short* xb    = (unsigned short*)ws; ws += (size_t)MTOK * HID * 2;
  unsigned short* Wqkvt = (unsigned short*)ws; ws += (size_t)NQKV * HID * 2;
  unsigned short* Wot   = (unsigned short*)ws; ws += (size_t)HID * HID * 2;
  float*          biasq = (float*)ws;          ws += (size_t)NQKV * 4;
  unsigned short* qkv   = (unsigned short*)ws; ws += (size_t)MTOK * NQKV * 2;
  unsigned short* attn  = (unsigned short*)ws; ws += (size_t)MTOK * HID * 2;

  (void)hipFuncSetAttribute((const void*)&gemm256<false>,
                            hipFuncAttributeMaxDynamicSharedMemorySize, RING);
  (void)hipFuncSetAttribute((const void*)&gemm256<true>,
                            hipFuncAttributeMaxDynamicSharedMemorySize, RING);

  convert_f32_bf16<<<4096, 256, 0, stream>>>(x, xb, MTOK * HID / 8);
  transpose4_to_bf16<<<dim3(32, 32, 4), 256, 0, stream>>>(Wq, Wk, Wv, Wo,
                                                          Wqkvt, Wot);
  concat_bias<<<24, 256, 0, stream>>>(bq, bk, bv, biasq);

  // QKV projection: [16384][2048] x [6144][2048]^T -> bf16 [16384][6144]
  gemm256<false><<<(MTOK / 256) * (NQKV / 256), 512, RING, stream>>>(
      xb, Wqkvt, biasq, qkv, nullptr, MTOK, NQKV);
  attn_kernel<<<MTOK / 4, 256, 0, stream>>>(qkv, attn, c_scale);
  // O projection: [16384][2048] x [2048][2048]^T -> f32 out
  gemm256<true><<<(MTOK / 256) * (HID / 256), 512, RING, stream>>>(
      attn, Wot, bo, nullptr, out, MTOK, HID);
}

// Round 4
// 836.674 us; speedup vs baseline: 1.2701x; 1.0108x over previous
//
#include <hip/hip_runtime.h>
#include <hip/hip_bf16.h>
#include <stdint.h>

// Problem constants
#define MTOK 16384   // B*S
#define HID  2048
#define NQKV 6144    // 3*HID
#define GK   2048    // K of both GEMMs
#define NKT  (GK / 64)    // 32 K-tiles
#define NREG (NKT * 4)    // 128 staging regions (A_k0,B_k0,A_k1,B_k1 per tile)
#define SLOT 16384        // bytes per LDS region slot
#define RING (9 * SLOT)   // 147456 B: 9-slot ring

typedef __attribute__((ext_vector_type(8))) short bf16x8;
typedef __attribute__((ext_vector_type(4))) float f32x4;

__device__ __forceinline__ unsigned short f2bf(float f) {
  uint32_t u = __float_as_uint(f);
  u = (u + 0x7FFFu + ((u >> 16) & 1u)) >> 16;   // round-to-nearest-even
  return (unsigned short)u;
}
__device__ __forceinline__ void bf2x2(uint32_t u, float& lo, float& hi) {
  lo = __uint_as_float(u << 16);
  hi = __uint_as_float(u & 0xFFFF0000u);
}

__device__ __forceinline__ void gld_lds16(const void* g, void* l) {
  __builtin_amdgcn_global_load_lds(
      (const __attribute__((address_space(1))) uint32_t*)g,
      (__attribute__((address_space(3))) uint32_t*)l, 16, 0, 0);
}

// ---------------- fp32 -> bf16 elementwise convert (8 elems/thread/iter) ---
__global__ void convert_f32_bf16(const float* __restrict__ in,
                                 unsigned short* __restrict__ out, int n8) {
  int idx = blockIdx.x * blockDim.x + threadIdx.x;
  int stride = gridDim.x * blockDim.x;
  for (int i = idx; i < n8; i += stride) {
    const float4* p = (const float4*)(in + (size_t)i * 8);
    float4 a = p[0], b = p[1];
    union { bf16x8 v; unsigned short u[8]; } o;
    o.u[0] = f2bf(a.x); o.u[1] = f2bf(a.y); o.u[2] = f2bf(a.z); o.u[3] = f2bf(a.w);
    o.u[4] = f2bf(b.x); o.u[5] = f2bf(b.y); o.u[6] = f2bf(b.z); o.u[7] = f2bf(b.w);
    *(bf16x8*)(out + (size_t)i * 8) = o.v;
  }
}

// ------- 4x W[K][N] f32 -> Wt[N][K] bf16 (64x64 LDS tiles), z picks W ------
__global__ void transpose4_to_bf16(const float* __restrict__ Wq,
                                   const float* __restrict__ Wk,
                                   const float* __restrict__ Wv,
                                   const float* __restrict__ Wo,
                                   unsigned short* __restrict__ Wqkvt,
                                   unsigned short* __restrict__ Wot) {
  __shared__ float tile[64][65];
  const float* W;
  unsigned short* Wt;
  const int z = blockIdx.z;
  if (z == 0)      { W = Wq; Wt = Wqkvt; }
  else if (z == 1) { W = Wk; Wt = Wqkvt + (size_t)HID * HID; }
  else if (z == 2) { W = Wv; Wt = Wqkvt + (size_t)2 * HID * HID; }
  else             { W = Wo; Wt = Wot; }
  int tk = blockIdx.x * 64, tn = blockIdx.y * 64;
  int t = threadIdx.x;
  int c = t & 63, rb = t >> 6;
#pragma unroll
  for (int i = 0; i < 16; i++) {
    int r = i * 4 + rb;
    tile[r][c] = W[(size_t)(tk + r) * HID + tn + c];
  }
  __syncthreads();
#pragma unroll
  for (int i = 0; i < 16; i++) {
    int r = i * 4 + rb;  // r = n index, c = k index
    Wt[(size_t)(tn + r) * HID + tk + c] = f2bf(tile[c][r]);
  }
}

// ---------------- bias concat [bq|bk|bv] -> [6144] f32 ---------------------
__global__ void concat_bias(const float* __restrict__ bq,
                            const float* __restrict__ bk,
                            const float* __restrict__ bv,
                            float* __restrict__ out) {
  int i = blockIdx.x * blockDim.x + threadIdx.x;
  if (i < 2048)       out[i] = bq[i];
  else if (i < 4096)  out[i] = bk[i - 2048];
  else if (i < 6144)  out[i] = bv[i - 4096];
}

// ===========================================================================
// 256x256 bf16 GEMM, burst-read 2-barrier-per-K-tile schedule.
//
// LDS: 9-slot ring of 16 KiB regions. Region S_J (J = 4u + {0:A_k0,1:B_k0,
// 2:A_k1,3:B_k1}) in slot J mod 9. Swizzle involution byte ^= ((row>>1)&3)<<4
// on ds_read addr, inverse pre-applied to global_load_lds source (rule #21).
//
// Per K-tile u (ledger-verified):
//   top:  STAGE S_{4u+7},S_{4u+8} (overwrite S_{4u-2},S_{4u-1}: tile u-1
//         regions, reads forced complete before B_close(u-1) by p3 MFMAs)
//         burst 16 ds_reads: A(k0,h0), B(k0), A(k0,h1), B(k1); sched_barrier
//   p0/p1 MFMA (compiler inserts counted lgkmcnt)
//         8 ds_reads A(k1,h0), A(k1,h1)  -- overlap p0/p1
//   mid:  lgkmcnt(12) [no-op safety pin] + s_barrier
//         STAGE S_{4u+9},S_{4u+10} (overwrite S_{4u},S_{4u+1}: their reads
//         1-12 complete before any wave passed mid-barrier)
//   p2/p3 MFMA; vmcnt(6) (3 regions in flight); s_barrier (close)
// ===========================================================================
template <bool F32OUT>
__global__ __launch_bounds__(512, 2) void gemm256(
    const unsigned short* __restrict__ A,   // [M][GK] bf16
    const unsigned short* __restrict__ Bt,  // [N][GK] bf16
    const float* __restrict__ bias,         // [N]
    unsigned short* __restrict__ Cb, float* __restrict__ Cf,
    int M, int N) {
  extern __shared__ __align__(16) char lds[];

  // XCD-bijective block swizzle (grid % 8 == 0 for both shapes)
  const int nwg = gridDim.x;
  const int bid = blockIdx.x;
  const int wg = (bid & 7) * (nwg >> 3) + (bid >> 3);
  const int ntm = M >> 8;
  const int tm = wg % ntm, tn = wg / ntm;

  const int tid = threadIdx.x;
  const int wave = tid >> 6, lane = tid & 63;
  const int wr = wave >> 2, wc = wave & 3;   // 2M x 4N waves, 128x64 out each

  // ---- staging addressing (per-thread, bytes) ----
  const int colb = ((tid & 3) << 4) ^ (((tid >> 3) & 3) << 4);
  const size_t g0 = (size_t)(tid >> 2) * (GK * 2) + colb;
  const size_t g1 = g0 + (size_t)128 * (GK * 2);
  const char* Ab = (const char*)A + (size_t)tm * 256 * (GK * 2);
  const char* Bb = (const char*)Bt + (size_t)tn * 256 * (GK * 2);

#define STAGE(J, DST)                                                     \
  do {                                                                    \
    if ((J) < NREG) {                                                     \
      const int _t = (J) >> 2;                                            \
      const char* _s = (((J)&1) ? Bb : Ab) + (size_t)(_t)*128 +           \
                       ((((J) >> 1) & 1) * 64);                           \
      char* _d = lds + (DST) + (wave << 10);                              \
      gld_lds16(_s + g0, _d);                                             \
      gld_lds16(_s + g1, _d + 8192);                                      \
    }                                                                     \
  } while (0)

  // ---- fragment read addressing ----
  const int fr = lane & 15;
  const int fkb = (lane >> 4) << 4;                           // k-offset bytes
  const int lofs = fr * 64 + (fkb ^ (((fr >> 1) & 3) << 4));  // swizzled

  f32x4 acc[8][4];
#pragma unroll
  for (int m = 0; m < 8; m++)
#pragma unroll
    for (int n = 0; n < 4; n++) acc[m][n] = (f32x4){0.f, 0.f, 0.f, 0.f};
  bf16x8 aA[4], aB[4], b0[4], b1[4];

  // ---- ring cursors: rs[i]=slot(S_{4u+i}); ws[j]=slot(S_{4u+7+j}) ----
  int rs[4] = {0, SLOT, 2 * SLOT, 3 * SLOT};
  int wsl[4] = {7 * SLOT, 8 * SLOT, 0, SLOT};

  // ---- prologue: stage S_0..S_6 into slots 0..6 ----
  STAGE(0, 0); STAGE(1, SLOT); STAGE(2, 2 * SLOT); STAGE(3, 3 * SLOT);
  STAGE(4, 4 * SLOT); STAGE(5, 5 * SLOT); STAGE(6, 6 * SLOT);
  asm volatile("s_waitcnt vmcnt(6)" ::: "memory");  // S_0..S_3 landed
  __builtin_amdgcn_s_barrier();

  for (int u = 0; u < NKT; ++u) {
    // ---- top: prefetch stages + fragment burst ----
    STAGE(u * 4 + 7, wsl[0]);
    STAGE(u * 4 + 8, wsl[1]);
    {
      const char* a0p = lds + rs[0] + wr * 8192 + lofs;
      const char* b0p = lds + rs[1] + wc * 4096 + lofs;
      const char* b1p = lds + rs[3] + wc * 4096 + lofs;
#pragma unroll
      for (int m = 0; m < 4; m++) aA[m] = *(const bf16x8*)(a0p + m * 1024);
#pragma unroll
      for (int n = 0; n < 4; n++) b0[n] = *(const bf16x8*)(b0p + n * 1024);
#pragma unroll
      for (int m = 0; m < 4; m++) aB[m] = *(const bf16x8*)(a0p + 4096 + m * 1024);
#pragma unroll
      for (int n = 0; n < 4; n++) b1[n] = *(const bf16x8*)(b1p + n * 1024);
    }
    __builtin_amdgcn_sched_barrier(0);  // pin burst above MFMA

    // ---- p0/p1: kstep0 (compiler inserts counted lgkmcnt) ----
    __builtin_amdgcn_s_setprio(1);
#pragma unroll
    for (int m = 0; m < 4; m++)
#pragma unroll
      for (int n = 0; n < 4; n++)
        acc[m][n] = __builtin_amdgcn_mfma_f32_16x16x32_bf16(aA[m], b0[n],
                                                            acc[m][n], 0, 0, 0);
#pragma unroll
    for (int m = 0; m < 4; m++)
#pragma unroll
      for (int n = 0; n < 4; n++)
        acc[4 + m][n] = __builtin_amdgcn_mfma_f32_16x16x32_bf16(
            aB[m], b0[n], acc[4 + m][n], 0, 0, 0);
    __builtin_amdgcn_s_setprio(0);

    // ---- A(k1) reads: overlap with p0/p1 issue above (in-flight) ----
    {
      const char* a1p = lds + rs[2] + wr * 8192 + lofs;
#pragma unroll
      for (int m = 0; m < 4; m++) aA[m] = *(const bf16x8*)(a1p + m * 1024);
#pragma unroll
      for (int m = 0; m < 4; m++) aB[m] = *(const bf16x8*)(a1p + 4096 + m * 1024);
    }
    // ---- mid barrier: WAR gate for S_{4u+9},S_{4u+10} overwrites ----
    asm volatile("s_waitcnt lgkmcnt(12)" ::: "memory");  // reads 1-12 done
    __builtin_amdgcn_s_barrier();
    STAGE(u * 4 + 9, wsl[2]);
    STAGE(u * 4 + 10, wsl[3]);
    __builtin_amdgcn_sched_barrier(0);  // pin stage issue before p2/p3

    // ---- p2/p3: kstep1 ----
    __builtin_amdgcn_s_setprio(1);
#pragma unroll
    for (int m = 0; m < 4; m++)
#pragma unroll
      for (int n = 0; n < 4; n++)
        acc[m][n] = __builtin_amdgcn_mfma_f32_16x16x32_bf16(aA[m], b1[n],
                                                            acc[m][n], 0, 0, 0);
#pragma unroll
    for (int m = 0; m < 4; m++)
#pragma unroll
      for (int n = 0; n < 4; n++)
        acc[4 + m][n] = __builtin_amdgcn_mfma_f32_16x16x32_bf16(
            aB[m], b1[n], acc[4 + m][n], 0, 0, 0);
    __builtin_amdgcn_s_setprio(0);

    asm volatile("s_waitcnt vmcnt(6)" ::: "memory");  // next tile landed
    __builtin_amdgcn_s_barrier();

#pragma unroll
    for (int i = 0; i < 4; i++) {
      rs[i] += 4 * SLOT;  if (rs[i] >= RING)  rs[i] -= RING;
      wsl[i] += 4 * SLOT; if (wsl[i] >= RING) wsl[i] -= RING;
    }
  }
#undef STAGE

  // ---- epilogue: C/D layout col=lane&15, row=(lane>>4)*4+reg ----
  const int fq = lane >> 4;
#pragma unroll
  for (int mp = 0; mp < 8; mp++) {
#pragma unroll
    for (int n = 0; n < 4; n++) {
      const int col = tn * 256 + wc * 64 + n * 16 + fr;
      const float bb = bias[col];
#pragma unroll
      for (int r = 0; r < 4; r++) {
        const int row = tm * 256 + wr * 128 + mp * 16 + fq * 4 + r;
        const float v = acc[mp][n][r] + bb;
        if constexpr (F32OUT) Cf[(size_t)row * N + col] = v;
        else                  Cb[(size_t)row * N + col] = f2bf(v);
      }
    }
  }
}

// ---------------- per-token 16x16 head-attention ---------------------------
__global__ __launch_bounds__(256) void attn_kernel(
    const unsigned short* __restrict__ qkv,  // [MTOK][6144] bf16
    unsigned short* __restrict__ attn,       // [MTOK][2048] bf16
    const float* __restrict__ c_scale) {
  constexpr int QS = 136;  // padded row stride (elements)
  __shared__ __align__(16) unsigned short qkvs[4][3][16 * QS];
  __shared__ float ps[4][16 * 17];

  const int wave = threadIdx.x >> 6, lane = threadIdx.x & 63;
  const int tok = blockIdx.x * 4 + wave;
  const unsigned short* src = qkv + (size_t)tok * NQKV;

  const int rr = lane >> 4;
  const int cc = (lane & 15) * 8;
#pragma unroll
  for (int mtx = 0; mtx < 3; mtx++) {
#pragma unroll
    for (int i = 0; i < 4; i++) {
      int h = i * 4 + rr;
      bf16x8 v = *(const bf16x8*)(src + mtx * HID + h * 128 + cc);
      *(bf16x8*)&qkvs[wave][mtx][h * QS + cc] = v;
    }
  }

  const float scale = c_scale[0] * 0.08838834764831845f;  // 1/sqrt(128)

  const int g = lane & 15;
#pragma unroll
  for (int it = 0; it < 4; it++) {
    int h = it * 4 + (lane >> 4);
    float s = 0.f;
#pragma unroll
    for (int c8 = 0; c8 < 16; c8++) {
      uint4 qv = *(const uint4*)&qkvs[wave][0][h * QS + c8 * 8];
      uint4 kv = *(const uint4*)&qkvs[wave][1][g * QS + c8 * 8];
      float ql, qh, kl, kh;
      bf2x2(qv.x, ql, qh); bf2x2(kv.x, kl, kh); s += ql * kl + qh * kh;
      bf2x2(qv.y, ql, qh); bf2x2(kv.y, kl, kh); s += ql * kl + qh * kh;
      bf2x2(qv.z, ql, qh); bf2x2(kv.z, kl, kh); s += ql * kl + qh * kh;
      bf2x2(qv.w, ql, qh); bf2x2(kv.w, kl, kh); s += ql * kl + qh * kh;
    }
    s *= scale;
    float mx = s;
    mx = fmaxf(mx, __shfl_xor(mx, 1));
    mx = fmaxf(mx, __shfl_xor(mx, 2));
    mx = fmaxf(mx, __shfl_xor(mx, 4));
    mx = fmaxf(mx, __shfl_xor(mx, 8));
    float e = __expf(s - mx);
    float sum = e;
    sum += __shfl_xor(sum, 1);
    sum += __shfl_xor(sum, 2);
    sum += __shfl_xor(sum, 4);
    sum += __shfl_xor(sum, 8);
    ps[wave][h * 17 + g] = e / sum;
  }

  const int h = lane >> 2;
  const int d0 = (lane & 3) * 32;
  float accv[32];
#pragma unroll
  for (int j = 0; j < 32; j++) accv[j] = 0.f;
#pragma unroll
  for (int gg = 0; gg < 16; gg++) {
    float p = ps[wave][h * 17 + gg];
#pragma unroll
    for (int c8 = 0; c8 < 4; c8++) {
      uint4 vv = *(const uint4*)&qkvs[wave][2][gg * QS + d0 + c8 * 8];
      float lo, hi;
      bf2x2(vv.x, lo, hi); accv[c8 * 8 + 0] += p * lo; accv[c8 * 8 + 1] += p * hi;
      bf2x2(vv.y, lo, hi); accv[c8 * 8 + 2] += p * lo; accv[c8 * 8 + 3] += p * hi;
      bf2x2(vv.z, lo, hi); accv[c8 * 8 + 4] += p * lo; accv[c8 * 8 + 5] += p * hi;
      bf2x2(vv.w, lo, hi); accv[c8 * 8 + 6] += p * lo; accv[c8 * 8 + 7] += p * hi;
    }
  }
  unsigned short* dst = attn + (size_t)tok * HID + h * 128 + d0;
#pragma unroll
  for (int c8 = 0; c8 < 4; c8++) {
    union { bf16x8 v; unsigned short u[8]; } o;
#pragma unroll
    for (int j = 0; j < 8; j++) o.u[j] = f2bf(accv[c8 * 8 + j]);
    *(bf16x8*)(dst + c8 * 8) = o.v;
  }
}

// ---------------------------------------------------------------------------
extern "C" void kernel_launch(void* const* d_in, const int* in_sizes, int n_in,
                              void* d_out, int out_size, void* d_ws,
                              size_t ws_size, hipStream_t stream) {
  const float* x  = (const float*)d_in[0];
  const float* Wq = (const float*)d_in[1];
  const float* bq = (const float*)d_in[2];
  const float* Wk = (const float*)d_in[3];
  const float* bk = (const float*)d_in[4];
  const float* Wv = (const float*)d_in[5];
  const float* bv = (const float*)d_in[6];
  const float* Wo = (const float*)d_in[7];
  const float* bo = (const float*)d_in[8];
  const float* c_scale = (const float*)d_in[9];
  float* out = (float*)d_out;

  char* ws = (char*)d_ws;
  unsigned short* xb    = (unsigned short*)ws; ws += (size_t)MTOK * HID * 2;
  unsigned short* Wqkvt = (unsigned short*)ws; ws += (size_t)NQKV * HID * 2;
  unsigned short* Wot   = (unsigned short*)ws; ws += (size_t)HID * HID * 2;
  float*          biasq = (float*)ws;          ws += (size_t)NQKV * 4;
  unsigned short* qkv   = (unsigned short*)ws; ws += (size_t)MTOK * NQKV * 2;
  unsigned short* attn  = (unsigned short*)ws; ws += (size_t)MTOK * HID * 2;

  (void)hipFuncSetAttribute((const void*)&gemm256<false>,
                            hipFuncAttributeMaxDynamicSharedMemorySize, RING);
  (void)hipFuncSetAttribute((const void*)&gemm256<true>,
                            hipFuncAttributeMaxDynamicSharedMemorySize, RING);

  convert_f32_bf16<<<2048, 256, 0, stream>>>(x, xb, MTOK * HID / 8);
  transpose4_to_bf16<<<dim3(32, 32, 4), 256, 0, stream>>>(Wq, Wk, Wv, Wo,
                                                          Wqkvt, Wot);
  concat_bias<<<24, 256, 0, stream>>>(bq, bk, bv, biasq);

  // QKV projection: [16384][2048] x [6144][2048]^T -> bf16 [16384][6144]
  gemm256<false><<<(MTOK / 256) * (NQKV / 256), 512, RING, stream>>>(
      xb, Wqkvt, biasq, qkv, nullptr, MTOK, NQKV);
  attn_kernel<<<MTOK / 4, 256, 0, stream>>>(qkv, attn, c_scale);
  // O projection: [16384][2048] x [2048][2048]^T -> f32 out
  gemm256<true><<<(MTOK / 256) * (HID / 256), 512, RING, stream>>>(
      attn, Wot, bo, nullptr, out, MTOK, HID);
}

// Round 5
// 792.644 us; speedup vs baseline: 1.3407x; 1.0555x over previous
//
#include <hip/hip_runtime.h>
#include <hip/hip_bf16.h>
#include <stdint.h>

// Problem constants
#define MTOK 16384   // B*S
#define HID  2048
#define NQKV 6144    // 3*HID
#define GK   2048    // K of both GEMMs
#define NKT  (GK / 64)    // 32 K-tiles
#define NREG (NKT * 4)    // 128 staging regions (A_k0,B_k0,A_k1,B_k1 per tile)
#define SLOT 16384        // bytes per LDS region slot
#define RING (9 * SLOT)   // 147456 B: 9-slot ring

typedef __attribute__((ext_vector_type(8))) short bf16x8;
typedef __attribute__((ext_vector_type(4))) float f32x4;

__device__ __forceinline__ unsigned short f2bf(float f) {
  uint32_t u = __float_as_uint(f);
  u = (u + 0x7FFFu + ((u >> 16) & 1u)) >> 16;   // round-to-nearest-even
  return (unsigned short)u;
}
__device__ __forceinline__ void bf2x2(uint32_t u, float& lo, float& hi) {
  lo = __uint_as_float(u << 16);
  hi = __uint_as_float(u & 0xFFFF0000u);
}

__device__ __forceinline__ void gld_lds16(const void* g, void* l) {
  __builtin_amdgcn_global_load_lds(
      (const __attribute__((address_space(1))) uint32_t*)g,
      (__attribute__((address_space(3))) uint32_t*)l, 16, 0, 0);
}

// ---------------- fp32 -> bf16 elementwise convert (8 elems/thread/iter) ---
__global__ void convert_f32_bf16(const float* __restrict__ in,
                                 unsigned short* __restrict__ out, int n8) {
  int idx = blockIdx.x * blockDim.x + threadIdx.x;
  int stride = gridDim.x * blockDim.x;
  for (int i = idx; i < n8; i += stride) {
    const float4* p = (const float4*)(in + (size_t)i * 8);
    float4 a = p[0], b = p[1];
    union { bf16x8 v; unsigned short u[8]; } o;
    o.u[0] = f2bf(a.x); o.u[1] = f2bf(a.y); o.u[2] = f2bf(a.z); o.u[3] = f2bf(a.w);
    o.u[4] = f2bf(b.x); o.u[5] = f2bf(b.y); o.u[6] = f2bf(b.z); o.u[7] = f2bf(b.w);
    *(bf16x8*)(out + (size_t)i * 8) = o.v;
  }
}

// ------- 4x W[K][N] f32 -> Wt[N][K] bf16 (64x64 LDS tiles), z picks W ------
__global__ void transpose4_to_bf16(const float* __restrict__ Wq,
                                   const float* __restrict__ Wk,
                                   const float* __restrict__ Wv,
                                   const float* __restrict__ Wo,
                                   unsigned short* __restrict__ Wqkvt,
                                   unsigned short* __restrict__ Wot) {
  __shared__ float tile[64][65];
  const float* W;
  unsigned short* Wt;
  const int z = blockIdx.z;
  if (z == 0)      { W = Wq; Wt = Wqkvt; }
  else if (z == 1) { W = Wk; Wt = Wqkvt + (size_t)HID * HID; }
  else if (z == 2) { W = Wv; Wt = Wqkvt + (size_t)2 * HID * HID; }
  else             { W = Wo; Wt = Wot; }
  int tk = blockIdx.x * 64, tn = blockIdx.y * 64;
  int t = threadIdx.x;
  int c = t & 63, rb = t >> 6;
#pragma unroll
  for (int i = 0; i < 16; i++) {
    int r = i * 4 + rb;
    tile[r][c] = W[(size_t)(tk + r) * HID + tn + c];
  }
  __syncthreads();
#pragma unroll
  for (int i = 0; i < 16; i++) {
    int r = i * 4 + rb;  // r = n index, c = k index
    Wt[(size_t)(tn + r) * HID + tk + c] = f2bf(tile[c][r]);
  }
}

// ---------------- bias concat [bq|bk|bv] -> [6144] f32 ---------------------
__global__ void concat_bias(const float* __restrict__ bq,
                            const float* __restrict__ bk,
                            const float* __restrict__ bv,
                            float* __restrict__ out) {
  int i = blockIdx.x * blockDim.x + threadIdx.x;
  if (i < 2048)       out[i] = bq[i];
  else if (i < 4096)  out[i] = bk[i - 2048];
  else if (i < 6144)  out[i] = bv[i - 4096];
}

// ===========================================================================
// 256x256 bf16 GEMM, burst-read 2-barrier-per-K-tile schedule.
//
// GRID MAPPING (r5): XCD x owns an exclusive 8-row A-band (tm = x*8 + i%8),
// walking tn = i/8 across it. A fetched from HBM once chip-wide (64 MB);
// concurrent 32 blocks/XCD span 8tm x 4tn -> B working set ~4 MB (L2);
// all XCDs walk the same tn columns together -> B L3-resident.
// Requires ntm == 64 (M == 16384) and grid % 8 == 0.
//
// LDS: 9-slot ring of 16 KiB regions. Region S_J (J = 4u + {0:A_k0,1:B_k0,
// 2:A_k1,3:B_k1}) in slot J mod 9. Swizzle involution byte ^= ((row>>1)&3)<<4
// on ds_read addr, inverse pre-applied to global_load_lds source (rule #21).
//
// Per K-tile u (ledger-verified):
//   top:  STAGE S_{4u+7},S_{4u+8}; burst 16 ds_reads (A k0 both halves, B k0,
//         B k1); sched_barrier
//   p0/p1 MFMA (counted lgkmcnt by compiler); then 8 ds_reads A(k1)
//   mid:  lgkmcnt(12) + s_barrier; STAGE S_{4u+9},S_{4u+10}
//   p2/p3 MFMA; vmcnt(6); s_barrier (close)
// ===========================================================================
template <bool F32OUT>
__global__ __launch_bounds__(512, 2) void gemm256(
    const unsigned short* __restrict__ A,   // [M][GK] bf16
    const unsigned short* __restrict__ Bt,  // [N][GK] bf16
    const float* __restrict__ bias,         // [N]
    unsigned short* __restrict__ Cb, float* __restrict__ Cf,
    int M, int N) {
  extern __shared__ __align__(16) char lds[];

  // ---- locality-aware XCD banding (ntm == 64 assumed) ----
  const int bid = blockIdx.x;
  const int xcd = bid & 7;
  const int i6 = bid >> 3;              // [0, nwg/8)
  const int tm = xcd * 8 + (i6 & 7);    // exclusive 8-row A-band per XCD
  const int tn = i6 >> 3;               // tn walked in lockstep across XCDs

  const int tid = threadIdx.x;
  const int wave = tid >> 6, lane = tid & 63;
  const int wr = wave >> 2, wc = wave & 3;   // 2M x 4N waves, 128x64 out each

  // ---- staging addressing (per-thread, bytes) ----
  const int colb = ((tid & 3) << 4) ^ (((tid >> 3) & 3) << 4);
  const size_t g0 = (size_t)(tid >> 2) * (GK * 2) + colb;
  const size_t g1 = g0 + (size_t)128 * (GK * 2);
  const char* Ab = (const char*)A + (size_t)tm * 256 * (GK * 2);
  const char* Bb = (const char*)Bt + (size_t)tn * 256 * (GK * 2);

#define STAGE(J, DST)                                                     \
  do {                                                                    \
    if ((J) < NREG) {                                                     \
      const int _t = (J) >> 2;                                            \
      const char* _s = (((J)&1) ? Bb : Ab) + (size_t)(_t)*128 +           \
                       ((((J) >> 1) & 1) * 64);                           \
      char* _d = lds + (DST) + (wave << 10);                              \
      gld_lds16(_s + g0, _d);                                             \
      gld_lds16(_s + g1, _d + 8192);                                      \
    }                                                                     \
  } while (0)

  // ---- fragment read addressing ----
  const int fr = lane & 15;
  const int fkb = (lane >> 4) << 4;                           // k-offset bytes
  const int lofs = fr * 64 + (fkb ^ (((fr >> 1) & 3) << 4));  // swizzled

  f32x4 acc[8][4];
#pragma unroll
  for (int m = 0; m < 8; m++)
#pragma unroll
    for (int n = 0; n < 4; n++) acc[m][n] = (f32x4){0.f, 0.f, 0.f, 0.f};
  bf16x8 aA[4], aB[4], b0[4], b1[4];

  // ---- ring cursors: rs[i]=slot(S_{4u+i}); wsl[j]=slot(S_{4u+7+j}) ----
  int rs[4] = {0, SLOT, 2 * SLOT, 3 * SLOT};
  int wsl[4] = {7 * SLOT, 8 * SLOT, 0, SLOT};

  // ---- prologue: stage S_0..S_6 into slots 0..6 ----
  STAGE(0, 0); STAGE(1, SLOT); STAGE(2, 2 * SLOT); STAGE(3, 3 * SLOT);
  STAGE(4, 4 * SLOT); STAGE(5, 5 * SLOT); STAGE(6, 6 * SLOT);
  asm volatile("s_waitcnt vmcnt(6)" ::: "memory");  // S_0..S_3 landed
  __builtin_amdgcn_s_barrier();

  for (int u = 0; u < NKT; ++u) {
    // ---- top: prefetch stages + fragment burst ----
    STAGE(u * 4 + 7, wsl[0]);
    STAGE(u * 4 + 8, wsl[1]);
    {
      const char* a0p = lds + rs[0] + wr * 8192 + lofs;
      const char* b0p = lds + rs[1] + wc * 4096 + lofs;
      const char* b1p = lds + rs[3] + wc * 4096 + lofs;
#pragma unroll
      for (int m = 0; m < 4; m++) aA[m] = *(const bf16x8*)(a0p + m * 1024);
#pragma unroll
      for (int n = 0; n < 4; n++) b0[n] = *(const bf16x8*)(b0p + n * 1024);
#pragma unroll
      for (int m = 0; m < 4; m++) aB[m] = *(const bf16x8*)(a0p + 4096 + m * 1024);
#pragma unroll
      for (int n = 0; n < 4; n++) b1[n] = *(const bf16x8*)(b1p + n * 1024);
    }
    __builtin_amdgcn_sched_barrier(0);  // pin burst above MFMA

    // ---- p0/p1: kstep0 (compiler inserts counted lgkmcnt) ----
    __builtin_amdgcn_s_setprio(1);
#pragma unroll
    for (int m = 0; m < 4; m++)
#pragma unroll
      for (int n = 0; n < 4; n++)
        acc[m][n] = __builtin_amdgcn_mfma_f32_16x16x32_bf16(aA[m], b0[n],
                                                            acc[m][n], 0, 0, 0);
#pragma unroll
    for (int m = 0; m < 4; m++)
#pragma unroll
      for (int n = 0; n < 4; n++)
        acc[4 + m][n] = __builtin_amdgcn_mfma_f32_16x16x32_bf16(
            aB[m], b0[n], acc[4 + m][n], 0, 0, 0);
    __builtin_amdgcn_s_setprio(0);

    // ---- A(k1) reads: overlap with p0/p1 issue above (in-flight) ----
    {
      const char* a1p = lds + rs[2] + wr * 8192 + lofs;
#pragma unroll
      for (int m = 0; m < 4; m++) aA[m] = *(const bf16x8*)(a1p + m * 1024);
#pragma unroll
      for (int m = 0; m < 4; m++) aB[m] = *(const bf16x8*)(a1p + 4096 + m * 1024);
    }
    // ---- mid barrier: WAR gate for S_{4u+9},S_{4u+10} overwrites ----
    asm volatile("s_waitcnt lgkmcnt(12)" ::: "memory");  // reads 1-12 done
    __builtin_amdgcn_s_barrier();
    STAGE(u * 4 + 9, wsl[2]);
    STAGE(u * 4 + 10, wsl[3]);
    __builtin_amdgcn_sched_barrier(0);  // pin stage issue before p2/p3

    // ---- p2/p3: kstep1 ----
    __builtin_amdgcn_s_setprio(1);
#pragma unroll
    for (int m = 0; m < 4; m++)
#pragma unroll
      for (int n = 0; n < 4; n++)
        acc[m][n] = __builtin_amdgcn_mfma_f32_16x16x32_bf16(aA[m], b1[n],
                                                            acc[m][n], 0, 0, 0);
#pragma unroll
    for (int m = 0; m < 4; m++)
#pragma unroll
      for (int n = 0; n < 4; n++)
        acc[4 + m][n] = __builtin_amdgcn_mfma_f32_16x16x32_bf16(
            aB[m], b1[n], acc[4 + m][n], 0, 0, 0);
    __builtin_amdgcn_s_setprio(0);

    asm volatile("s_waitcnt vmcnt(6)" ::: "memory");  // next tile landed
    __builtin_amdgcn_s_barrier();

#pragma unroll
    for (int i = 0; i < 4; i++) {
      rs[i] += 4 * SLOT;  if (rs[i] >= RING)  rs[i] -= RING;
      wsl[i] += 4 * SLOT; if (wsl[i] >= RING) wsl[i] -= RING;
    }
  }
#undef STAGE

  // ---- epilogue: C/D layout col=lane&15, row=(lane>>4)*4+reg ----
  const int fq = lane >> 4;
#pragma unroll
  for (int mp = 0; mp < 8; mp++) {
#pragma unroll
    for (int n = 0; n < 4; n++) {
      const int col = tn * 256 + wc * 64 + n * 16 + fr;
      const float bb = bias[col];
#pragma unroll
      for (int r = 0; r < 4; r++) {
        const int row = tm * 256 + wr * 128 + mp * 16 + fq * 4 + r;
        const float v = acc[mp][n][r] + bb;
        if constexpr (F32OUT) Cf[(size_t)row * N + col] = v;
        else                  Cb[(size_t)row * N + col] = f2bf(v);
      }
    }
  }
}

// ---------------- per-token 16x16 head-attention ---------------------------
__global__ __launch_bounds__(256) void attn_kernel(
    const unsigned short* __restrict__ qkv,  // [MTOK][6144] bf16
    unsigned short* __restrict__ attn,       // [MTOK][2048] bf16
    const float* __restrict__ c_scale) {
  constexpr int QS = 136;  // padded row stride (elements)
  __shared__ __align__(16) unsigned short qkvs[4][3][16 * QS];
  __shared__ float ps[4][16 * 17];

  const int wave = threadIdx.x >> 6, lane = threadIdx.x & 63;
  const int tok = blockIdx.x * 4 + wave;
  const unsigned short* src = qkv + (size_t)tok * NQKV;

  const int rr = lane >> 4;
  const int cc = (lane & 15) * 8;
#pragma unroll
  for (int mtx = 0; mtx < 3; mtx++) {
#pragma unroll
    for (int i = 0; i < 4; i++) {
      int h = i * 4 + rr;
      bf16x8 v = *(const bf16x8*)(src + mtx * HID + h * 128 + cc);
      *(bf16x8*)&qkvs[wave][mtx][h * QS + cc] = v;
    }
  }

  const float scale = c_scale[0] * 0.08838834764831845f;  // 1/sqrt(128)

  const int g = lane & 15;
#pragma unroll
  for (int it = 0; it < 4; it++) {
    int h = it * 4 + (lane >> 4);
    float s = 0.f;
#pragma unroll
    for (int c8 = 0; c8 < 16; c8++) {
      uint4 qv = *(const uint4*)&qkvs[wave][0][h * QS + c8 * 8];
      uint4 kv = *(const uint4*)&qkvs[wave][1][g * QS + c8 * 8];
      float ql, qh, kl, kh;
      bf2x2(qv.x, ql, qh); bf2x2(kv.x, kl, kh); s += ql * kl + qh * kh;
      bf2x2(qv.y, ql, qh); bf2x2(kv.y, kl, kh); s += ql * kl + qh * kh;
      bf2x2(qv.z, ql, qh); bf2x2(kv.z, kl, kh); s += ql * kl + qh * kh;
      bf2x2(qv.w, ql, qh); bf2x2(kv.w, kl, kh); s += ql * kl + qh * kh;
    }
    s *= scale;
    float mx = s;
    mx = fmaxf(mx, __shfl_xor(mx, 1));
    mx = fmaxf(mx, __shfl_xor(mx, 2));
    mx = fmaxf(mx, __shfl_xor(mx, 4));
    mx = fmaxf(mx, __shfl_xor(mx, 8));
    float e = __expf(s - mx);
    float sum = e;
    sum += __shfl_xor(sum, 1);
    sum += __shfl_xor(sum, 2);
    sum += __shfl_xor(sum, 4);
    sum += __shfl_xor(sum, 8);
    ps[wave][h * 17 + g] = e / sum;
  }

  const int h = lane >> 2;
  const int d0 = (lane & 3) * 32;
  float accv[32];
#pragma unroll
  for (int j = 0; j < 32; j++) accv[j] = 0.f;
#pragma unroll
  for (int gg = 0; gg < 16; gg++) {
    float p = ps[wave][h * 17 + gg];
#pragma unroll
    for (int c8 = 0; c8 < 4; c8++) {
      uint4 vv = *(const uint4*)&qkvs[wave][2][gg * QS + d0 + c8 * 8];
      float lo, hi;
      bf2x2(vv.x, lo, hi); accv[c8 * 8 + 0] += p * lo; accv[c8 * 8 + 1] += p * hi;
      bf2x2(vv.y, lo, hi); accv[c8 * 8 + 2] += p * lo; accv[c8 * 8 + 3] += p * hi;
      bf2x2(vv.z, lo, hi); accv[c8 * 8 + 4] += p * lo; accv[c8 * 8 + 5] += p * hi;
      bf2x2(vv.w, lo, hi); accv[c8 * 8 + 6] += p * lo; accv[c8 * 8 + 7] += p * hi;
    }
  }
  unsigned short* dst = attn + (size_t)tok * HID + h * 128 + d0;
#pragma unroll
  for (int c8 = 0; c8 < 4; c8++) {
    union { bf16x8 v; unsigned short u[8]; } o;
#pragma unroll
    for (int j = 0; j < 8; j++) o.u[j] = f2bf(accv[c8 * 8 + j]);
    *(bf16x8*)(dst + c8 * 8) = o.v;
  }
}

// ---------------------------------------------------------------------------
extern "C" void kernel_launch(void* const* d_in, const int* in_sizes, int n_in,
                              void* d_out, int out_size, void* d_ws,
                              size_t ws_size, hipStream_t stream) {
  const float* x  = (const float*)d_in[0];
  const float* Wq = (const float*)d_in[1];
  const float* bq = (const float*)d_in[2];
  const float* Wk = (const float*)d_in[3];
  const float* bk = (const float*)d_in[4];
  const float* Wv = (const float*)d_in[5];
  const float* bv = (const float*)d_in[6];
  const float* Wo = (const float*)d_in[7];
  const float* bo = (const float*)d_in[8];
  const float* c_scale = (const float*)d_in[9];
  float* out = (float*)d_out;

  char* ws = (char*)d_ws;
  unsigned short* xb    = (unsigned short*)ws; ws += (size_t)MTOK * HID * 2;
  unsigned short* Wqkvt = (unsigned short*)ws; ws += (size_t)NQKV * HID * 2;
  unsigned short* Wot   = (unsigned short*)ws; ws += (size_t)HID * HID * 2;
  float*          biasq = (float*)ws;          ws += (size_t)NQKV * 4;
  unsigned short* qkv   = (unsigned short*)ws; ws += (size_t)MTOK * NQKV * 2;
  unsigned short* attn  = (unsigned short*)ws; ws += (size_t)MTOK * HID * 2;

  (void)hipFuncSetAttribute((const void*)&gemm256<false>,
                            hipFuncAttributeMaxDynamicSharedMemorySize, RING);
  (void)hipFuncSetAttribute((const void*)&gemm256<true>,
                            hipFuncAttributeMaxDynamicSharedMemorySize, RING);

  convert_f32_bf16<<<2048, 256, 0, stream>>>(x, xb, MTOK * HID / 8);
  transpose4_to_bf16<<<dim3(32, 32, 4), 256, 0, stream>>>(Wq, Wk, Wv, Wo,
                                                          Wqkvt, Wot);
  concat_bias<<<24, 256, 0, stream>>>(bq, bk, bv, biasq);

  // QKV projection: [16384][2048] x [6144][2048]^T -> bf16 [16384][6144]
  gemm256<false><<<(MTOK / 256) * (NQKV / 256), 512, RING, stream>>>(
      xb, Wqkvt, biasq, qkv, nullptr, MTOK, NQKV);
  attn_kernel<<<MTOK / 4, 256, 0, stream>>>(qkv, attn, c_scale);
  // O projection: [16384][2048] x [2048][2048]^T -> f32 out
  gemm256<true><<<(MTOK / 256) * (HID / 256), 512, RING, stream>>>(
      attn, Wot, bo, nullptr, out, MTOK, HID);
}

// Round 7
// 615.686 us; speedup vs baseline: 1.7260x; 1.2874x over previous
//
#include <hip/hip_runtime.h>
#include <hip/hip_bf16.h>
#include <stdint.h>

// Problem constants
#define MTOK 16384   // B*S
#define HID  2048
#define NQKV 6144    // 3*HID
#define GK   2048    // K of both GEMMs
#define NKT  (GK / 64)    // 32 K-tiles
#define NREG (NKT * 4)    // 128 staging regions (A_k0,B_k0,A_k1,B_k1 per tile)
#define SLOT 16384        // bytes per LDS region slot
#define RING (9 * SLOT)   // 147456 B: 9-slot ring

typedef __attribute__((ext_vector_type(8))) short bf16x8;
typedef __attribute__((ext_vector_type(4))) float f32x4;

__device__ __forceinline__ unsigned short f2bf(float f) {
  uint32_t u = __float_as_uint(f);
  u = (u + 0x7FFFu + ((u >> 16) & 1u)) >> 16;   // round-to-nearest-even
  return (unsigned short)u;
}
__device__ __forceinline__ void bf2x2(uint32_t u, float& lo, float& hi) {
  lo = __uint_as_float(u << 16);
  hi = __uint_as_float(u & 0xFFFF0000u);
}

__device__ __forceinline__ void gld_lds16(const void* g, void* l) {
  __builtin_amdgcn_global_load_lds(
      (const __attribute__((address_space(1))) uint32_t*)g,
      (__attribute__((address_space(3))) uint32_t*)l, 16, 0, 0);
}

// ---------------- fp32 -> bf16 elementwise convert (8 elems/thread/iter) ---
__global__ void convert_f32_bf16(const float* __restrict__ in,
                                 unsigned short* __restrict__ out, int n8) {
  int idx = blockIdx.x * blockDim.x + threadIdx.x;
  int stride = gridDim.x * blockDim.x;
  for (int i = idx; i < n8; i += stride) {
    const float4* p = (const float4*)(in + (size_t)i * 8);
    float4 a = p[0], b = p[1];
    union { bf16x8 v; unsigned short u[8]; } o;
    o.u[0] = f2bf(a.x); o.u[1] = f2bf(a.y); o.u[2] = f2bf(a.z); o.u[3] = f2bf(a.w);
    o.u[4] = f2bf(b.x); o.u[5] = f2bf(b.y); o.u[6] = f2bf(b.z); o.u[7] = f2bf(b.w);
    *(bf16x8*)(out + (size_t)i * 8) = o.v;
  }
}

// ------- 4x W[K][N] f32 -> Wt[N][K] bf16 (64x64 LDS tiles), z picks W ------
__global__ void transpose4_to_bf16(const float* __restrict__ Wq,
                                   const float* __restrict__ Wk,
                                   const float* __restrict__ Wv,
                                   const float* __restrict__ Wo,
                                   unsigned short* __restrict__ Wqkvt,
                                   unsigned short* __restrict__ Wot) {
  __shared__ float tile[64][65];
  const float* W;
  unsigned short* Wt;
  const int z = blockIdx.z;
  if (z == 0)      { W = Wq; Wt = Wqkvt; }
  else if (z == 1) { W = Wk; Wt = Wqkvt + (size_t)HID * HID; }
  else if (z == 2) { W = Wv; Wt = Wqkvt + (size_t)2 * HID * HID; }
  else             { W = Wo; Wt = Wot; }
  int tk = blockIdx.x * 64, tn = blockIdx.y * 64;
  int t = threadIdx.x;
  int c = t & 63, rb = t >> 6;
#pragma unroll
  for (int i = 0; i < 16; i++) {
    int r = i * 4 + rb;
    tile[r][c] = W[(size_t)(tk + r) * HID + tn + c];
  }
  __syncthreads();
#pragma unroll
  for (int i = 0; i < 16; i++) {
    int r = i * 4 + rb;  // r = n index, c = k index
    Wt[(size_t)(tn + r) * HID + tk + c] = f2bf(tile[c][r]);
  }
}

// ---------------- bias concat [bq|bk|bv] -> [6144] f32 ---------------------
__global__ void concat_bias(const float* __restrict__ bq,
                            const float* __restrict__ bk,
                            const float* __restrict__ bv,
                            float* __restrict__ out) {
  int i = blockIdx.x * blockDim.x + threadIdx.x;
  if (i < 2048)       out[i] = bq[i];
  else if (i < 4096)  out[i] = bk[i - 2048];
  else if (i < 6144)  out[i] = bv[i - 4096];
}

// ===========================================================================
// 256x256 bf16 GEMM, burst-read 2-barrier-per-K-tile schedule (unchanged r5).
// ===========================================================================
template <bool F32OUT>
__global__ __launch_bounds__(512, 2) void gemm256(
    const unsigned short* __restrict__ A,   // [M][GK] bf16
    const unsigned short* __restrict__ Bt,  // [N][GK] bf16
    const float* __restrict__ bias,         // [N]
    unsigned short* __restrict__ Cb, float* __restrict__ Cf,
    int M, int N) {
  extern __shared__ __align__(16) char lds[];

  // ---- locality-aware XCD banding (ntm == 64 assumed) ----
  const int bid = blockIdx.x;
  const int xcd = bid & 7;
  const int i6 = bid >> 3;              // [0, nwg/8)
  const int tm = xcd * 8 + (i6 & 7);    // exclusive 8-row A-band per XCD
  const int tn = i6 >> 3;               // tn walked in lockstep across XCDs

  const int tid = threadIdx.x;
  const int wave = tid >> 6, lane = tid & 63;
  const int wr = wave >> 2, wc = wave & 3;   // 2M x 4N waves, 128x64 out each

  // ---- staging addressing (per-thread, bytes) ----
  const int colb = ((tid & 3) << 4) ^ (((tid >> 3) & 3) << 4);
  const size_t g0 = (size_t)(tid >> 2) * (GK * 2) + colb;
  const size_t g1 = g0 + (size_t)128 * (GK * 2);
  const char* Ab = (const char*)A + (size_t)tm * 256 * (GK * 2);
  const char* Bb = (const char*)Bt + (size_t)tn * 256 * (GK * 2);

#define STAGE(J, DST)                                                     \
  do {                                                                    \
    if ((J) < NREG) {                                                     \
      const int _t = (J) >> 2;                                            \
      const char* _s = (((J)&1) ? Bb : Ab) + (size_t)(_t)*128 +           \
                       ((((J) >> 1) & 1) * 64);                           \
      char* _d = lds + (DST) + (wave << 10);                              \
      gld_lds16(_s + g0, _d);                                             \
      gld_lds16(_s + g1, _d + 8192);                                      \
    }                                                                     \
  } while (0)

  // ---- fragment read addressing ----
  const int fr = lane & 15;
  const int fkb = (lane >> 4) << 4;                           // k-offset bytes
  const int lofs = fr * 64 + (fkb ^ (((fr >> 1) & 3) << 4));  // swizzled

  f32x4 acc[8][4];
#pragma unroll
  for (int m = 0; m < 8; m++)
#pragma unroll
    for (int n = 0; n < 4; n++) acc[m][n] = (f32x4){0.f, 0.f, 0.f, 0.f};
  bf16x8 aA[4], aB[4], b0[4], b1[4];

  // ---- ring cursors: rs[i]=slot(S_{4u+i}); wsl[j]=slot(S_{4u+7+j}) ----
  int rs[4] = {0, SLOT, 2 * SLOT, 3 * SLOT};
  int wsl[4] = {7 * SLOT, 8 * SLOT, 0, SLOT};

  // ---- prologue: stage S_0..S_6 into slots 0..6 ----
  STAGE(0, 0); STAGE(1, SLOT); STAGE(2, 2 * SLOT); STAGE(3, 3 * SLOT);
  STAGE(4, 4 * SLOT); STAGE(5, 5 * SLOT); STAGE(6, 6 * SLOT);
  asm volatile("s_waitcnt vmcnt(6)" ::: "memory");  // S_0..S_3 landed
  __builtin_amdgcn_s_barrier();

  for (int u = 0; u < NKT; ++u) {
    // ---- top: prefetch stages + fragment burst ----
    STAGE(u * 4 + 7, wsl[0]);
    STAGE(u * 4 + 8, wsl[1]);
    {
      const char* a0p = lds + rs[0] + wr * 8192 + lofs;
      const char* b0p = lds + rs[1] + wc * 4096 + lofs;
      const char* b1p = lds + rs[3] + wc * 4096 + lofs;
#pragma unroll
      for (int m = 0; m < 4; m++) aA[m] = *(const bf16x8*)(a0p + m * 1024);
#pragma unroll
      for (int n = 0; n < 4; n++) b0[n] = *(const bf16x8*)(b0p + n * 1024);
#pragma unroll
      for (int m = 0; m < 4; m++) aB[m] = *(const bf16x8*)(a0p + 4096 + m * 1024);
#pragma unroll
      for (int n = 0; n < 4; n++) b1[n] = *(const bf16x8*)(b1p + n * 1024);
    }
    __builtin_amdgcn_sched_barrier(0);  // pin burst above MFMA

    // ---- p0/p1: kstep0 (compiler inserts counted lgkmcnt) ----
    __builtin_amdgcn_s_setprio(1);
#pragma unroll
    for (int m = 0; m < 4; m++)
#pragma unroll
      for (int n = 0; n < 4; n++)
        acc[m][n] = __builtin_amdgcn_mfma_f32_16x16x32_bf16(aA[m], b0[n],
                                                            acc[m][n], 0, 0, 0);
#pragma unroll
    for (int m = 0; m < 4; m++)
#pragma unroll
      for (int n = 0; n < 4; n++)
        acc[4 + m][n] = __builtin_amdgcn_mfma_f32_16x16x32_bf16(
            aB[m], b0[n], acc[4 + m][n], 0, 0, 0);
    __builtin_amdgcn_s_setprio(0);

    // ---- A(k1) reads: overlap with p0/p1 issue above (in-flight) ----
    {
      const char* a1p = lds + rs[2] + wr * 8192 + lofs;
#pragma unroll
      for (int m = 0; m < 4; m++) aA[m] = *(const bf16x8*)(a1p + m * 1024);
#pragma unroll
      for (int m = 0; m < 4; m++) aB[m] = *(const bf16x8*)(a1p + 4096 + m * 1024);
    }
    // ---- mid barrier: WAR gate for S_{4u+9},S_{4u+10} overwrites ----
    asm volatile("s_waitcnt lgkmcnt(12)" ::: "memory");  // reads 1-12 done
    __builtin_amdgcn_s_barrier();
    STAGE(u * 4 + 9, wsl[2]);
    STAGE(u * 4 + 10, wsl[3]);
    __builtin_amdgcn_sched_barrier(0);  // pin stage issue before p2/p3

    // ---- p2/p3: kstep1 ----
    __builtin_amdgcn_s_setprio(1);
#pragma unroll
    for (int m = 0; m < 4; m++)
#pragma unroll
      for (int n = 0; n < 4; n++)
        acc[m][n] = __builtin_amdgcn_mfma_f32_16x16x32_bf16(aA[m], b1[n],
                                                            acc[m][n], 0, 0, 0);
#pragma unroll
    for (int m = 0; m < 4; m++)
#pragma unroll
      for (int n = 0; n < 4; n++)
        acc[4 + m][n] = __builtin_amdgcn_mfma_f32_16x16x32_bf16(
            aB[m], b1[n], acc[4 + m][n], 0, 0, 0);
    __builtin_amdgcn_s_setprio(0);

    asm volatile("s_waitcnt vmcnt(6)" ::: "memory");  // next tile landed
    __builtin_amdgcn_s_barrier();

#pragma unroll
    for (int i = 0; i < 4; i++) {
      rs[i] += 4 * SLOT;  if (rs[i] >= RING)  rs[i] -= RING;
      wsl[i] += 4 * SLOT; if (wsl[i] >= RING) wsl[i] -= RING;
    }
  }
#undef STAGE

  // ---- epilogue: C/D layout col=lane&15, row=(lane>>4)*4+reg ----
  const int fq = lane >> 4;
#pragma unroll
  for (int mp = 0; mp < 8; mp++) {
#pragma unroll
    for (int n = 0; n < 4; n++) {
      const int col = tn * 256 + wc * 64 + n * 16 + fr;
      const float bb = bias[col];
#pragma unroll
      for (int r = 0; r < 4; r++) {
        const int row = tm * 256 + wr * 128 + mp * 16 + fq * 4 + r;
        const float v = acc[mp][n][r] + bb;
        if constexpr (F32OUT) Cf[(size_t)row * N + col] = v;
        else                  Cb[(size_t)row * N + col] = f2bf(v);
      }
    }
  }
}

// ===========================================================================
// MFMA per-token head-attention (v4). 1 wave/token, 4 waves/block, NO LDS.
//
// Correctness rests only on verified facts:
//  - C/D layout col=lane&15, row=(lane>>4)*4+reg (m89).
//  - A/B input k-mapping is unknown but IDENTICAL for A and B (proven by
//    gemm256 passing with identical-function operand reads). Hence any
//    bijective assumed mapping kappa_as(hi,j) used consistently for BOTH
//    operands of one mfma cancels.
//
// QK^T: S^T = mfma(K,Q), both operands read with the same addressing
//   function -> lane holds S[g=(lane>>4)*4+r][h=lane&15] (verified C/D).
// Softmax over g: 3 in-lane + 2 shfl_xor (16,32).
// PV: kappa_as(hi,j) = hi*8+j for BOTH P-frag (shfl from C/D-layout regs,
//   zero for g>=16) and V-frag (scalar global loads V[(hi&1)*8+j][d];
//   hi>=2 slots multiply against P=0 -> exact zero contribution).
// ===========================================================================
__global__ __launch_bounds__(256) void attn_mfma(
    const unsigned short* __restrict__ qkv,  // [MTOK][6144] bf16
    unsigned short* __restrict__ attn,       // [MTOK][2048] bf16
    const float* __restrict__ c_scale) {
  const int wave = threadIdx.x >> 6, lane = threadIdx.x & 63;
  const int tok = blockIdx.x * 4 + wave;
  const unsigned short* src = qkv + (size_t)tok * NQKV;
  const int fr = lane & 15;
  const int hi = lane >> 4;

  // ---- Q,K fragments straight from global (identical addressing) ----
  const int fk = hi * 8;
  bf16x8 qf[4], kf[4];
#pragma unroll
  for (int kc = 0; kc < 4; kc++) {
    qf[kc] = *(const bf16x8*)(src + fr * 128 + kc * 32 + fk);
    kf[kc] = *(const bf16x8*)(src + HID + fr * 128 + kc * 32 + fk);
  }

  // ---- S^T = K . Q^T : lane holds S[g=hi*4+r][h=fr] ----
  f32x4 s = (f32x4){0.f, 0.f, 0.f, 0.f};
#pragma unroll
  for (int kc = 0; kc < 4; kc++)
    s = __builtin_amdgcn_mfma_f32_16x16x32_bf16(kf[kc], qf[kc], s, 0, 0, 0);

  const float scale = c_scale[0] * 0.08838834764831845f;  // 1/sqrt(128)
  float pa[4];
#pragma unroll
  for (int r = 0; r < 4; r++) pa[r] = s[r] * scale;

  // ---- softmax over g (rows): in-lane 4 + cross lane-group 16,32 ----
  float mx = fmaxf(fmaxf(pa[0], pa[1]), fmaxf(pa[2], pa[3]));
  mx = fmaxf(mx, __shfl_xor(mx, 16));
  mx = fmaxf(mx, __shfl_xor(mx, 32));
#pragma unroll
  for (int r = 0; r < 4; r++) pa[r] = __expf(pa[r] - mx);
  float sum = pa[0] + pa[1] + pa[2] + pa[3];
  sum += __shfl_xor(sum, 16);
  sum += __shfl_xor(sum, 32);
  float rsum = 1.0f / sum;
#pragma unroll
  for (int r = 0; r < 4; r++) pa[r] *= rsum;

  // ---- P A-frag: slot (hi,j) holds P[h=fr][g=hi*8+j], zero for g>=16.
  //      Source lane for P[fr][g'] is (g'>>2)*16 + fr, register g'&3. ----
  union { bf16x8 v; unsigned short u[8]; uint32_t w[4]; } pf;
  const int sidx0 = fr + (hi * 2) * 16;
#pragma unroll
  for (int j = 0; j < 8; j++) {
    float pv_ = __shfl(pa[j & 3], sidx0 + (j >> 2) * 16);
    pf.u[j] = f2bf(pv_);
  }
  if (lane >= 32) { pf.w[0] = 0; pf.w[1] = 0; pf.w[2] = 0; pf.w[3] = 0; }

  // ---- PV: V-frag slot (hi,j) = V[(hi&1)*8+j][d=dc*16+fr] via scalar
  //      global loads (same kappa_as as P for hi<2; hi>=2 x P=0 = 0). ----
  const unsigned short* vrow = src + 2 * HID + (hi & 1) * 8 * 128 + fr;
  unsigned short* dst = attn + (size_t)tok * HID;
#pragma unroll
  for (int dc = 0; dc < 8; dc++) {
    union { bf16x8 v; unsigned short u[8]; } vf;
#pragma unroll
    for (int j = 0; j < 8; j++) vf.u[j] = vrow[j * 128 + dc * 16];
    f32x4 o = __builtin_amdgcn_mfma_f32_16x16x32_bf16(
        pf.v, vf.v, (f32x4){0.f, 0.f, 0.f, 0.f}, 0, 0, 0);
#pragma unroll
    for (int r = 0; r < 4; r++)
      dst[(hi * 4 + r) * 128 + dc * 16 + fr] = f2bf(o[r]);
  }
}

// ---------------------------------------------------------------------------
extern "C" void kernel_launch(void* const* d_in, const int* in_sizes, int n_in,
                              void* d_out, int out_size, void* d_ws,
                              size_t ws_size, hipStream_t stream) {
  const float* x  = (const float*)d_in[0];
  const float* Wq = (const float*)d_in[1];
  const float* bq = (const float*)d_in[2];
  const float* Wk = (const float*)d_in[3];
  const float* bk = (const float*)d_in[4];
  const float* Wv = (const float*)d_in[5];
  const float* bv = (const float*)d_in[6];
  const float* Wo = (const float*)d_in[7];
  const float* bo = (const float*)d_in[8];
  const float* c_scale = (const float*)d_in[9];
  float* out = (float*)d_out;

  char* ws = (char*)d_ws;
  unsigned short* xb    = (unsigned short*)ws; ws += (size_t)MTOK * HID * 2;
  unsigned short* Wqkvt = (unsigned short*)ws; ws += (size_t)NQKV * HID * 2;
  unsigned short* Wot   = (unsigned short*)ws; ws += (size_t)HID * HID * 2;
  float*          biasq = (float*)ws;          ws += (size_t)NQKV * 4;
  unsigned short* qkv   = (unsigned short*)ws; ws += (size_t)MTOK * NQKV * 2;
  unsigned short* attn  = (unsigned short*)ws; ws += (size_t)MTOK * HID * 2;

  (void)hipFuncSetAttribute((const void*)&gemm256<false>,
                            hipFuncAttributeMaxDynamicSharedMemorySize, RING);
  (void)hipFuncSetAttribute((const void*)&gemm256<true>,
                            hipFuncAttributeMaxDynamicSharedMemorySize, RING);

  convert_f32_bf16<<<2048, 256, 0, stream>>>(x, xb, MTOK * HID / 8);
  transpose4_to_bf16<<<dim3(32, 32, 4), 256, 0, stream>>>(Wq, Wk, Wv, Wo,
                                                          Wqkvt, Wot);
  concat_bias<<<24, 256, 0, stream>>>(bq, bk, bv, biasq);

  // QKV projection: [16384][2048] x [6144][2048]^T -> bf16 [16384][6144]
  gemm256<false><<<(MTOK / 256) * (NQKV / 256), 512, RING, stream>>>(
      xb, Wqkvt, biasq, qkv, nullptr, MTOK, NQKV);
  attn_mfma<<<MTOK / 4, 256, 0, stream>>>(qkv, attn, c_scale);
  // O projection: [16384][2048] x [2048][2048]^T -> f32 out
  gemm256<true><<<(MTOK / 256) * (HID / 256), 512, RING, stream>>>(
      attn, Wot, bo, nullptr, out, MTOK, HID);
}